// Round 6
// baseline (709.720 us; speedup 1.0000x reference)
//
#include <hip/hip_runtime.h>

// Decoder block, MI355X gfx950. ALL float tensors f32 (per reference); ints
// int32; output f32. GEMMs + attention use bf16 MFMA internally, f32
// accumulate; residual stream kept in f32.

#define BB 16
#define SS 1024
#define DD 512
#define HH 8
#define DH 64
#define KTOT 1792          // 1024 + 512 + 256 pyramid keys
#define NROW (BB*SS)       // 16384
#define KSW 80             // attn LDS row stride (u16): 40 dwords == 8 mod 32 -> conflict-free

typedef unsigned short u16;
typedef __attribute__((ext_vector_type(8))) u16 u16x8;
typedef __attribute__((ext_vector_type(4))) u16 u16x4;
typedef __attribute__((ext_vector_type(8))) short s16x8;
typedef __attribute__((ext_vector_type(4))) float f32x4;

__device__ __forceinline__ float b2f(u16 u) {
    return __uint_as_float(((unsigned int)u) << 16);
}
__device__ __forceinline__ u16 f2b(float f) {
    unsigned int u = __float_as_uint(f);
    return (u16)((u + 0x7FFF + ((u >> 16) & 1)) >> 16);
}
__device__ __forceinline__ s16x8 u2s8(u16x8 u) {
    union { u16x8 u; s16x8 s; } x; x.u = u; return x.s;
}
__device__ __forceinline__ f32x4 mfma16(s16x8 a, s16x8 b, f32x4 c) {
    return __builtin_amdgcn_mfma_f32_16x16x32_bf16(a, b, c, 0, 0, 0);
}
__device__ __forceinline__ float wave_sum(float v) {
    #pragma unroll
    for (int m = 1; m < 64; m <<= 1) v += __shfl_xor(v, m, 64);
    return v;
}
// native 2^x
__device__ __forceinline__ float exp2a(float x) {
    float r;
    asm("v_exp_f32 %0, %1" : "=v"(r) : "v"(x));
    return r;
}
// packed bf16 convert (RNE): low16 = bf16(a), high16 = bf16(b)
__device__ __forceinline__ unsigned int cvtpk(float a, float b) {
    unsigned int r;
    asm("v_cvt_pk_bf16_f32 %0, %1, %2" : "=v"(r) : "v"(a), "v"(b));
    return r;
}
// async global->LDS 16B: per-lane global addr, LDS dest = wave-uniform base + lane*16
__device__ __forceinline__ void gl16(const void* g, void* l) {
    __builtin_amdgcn_global_load_lds(
        (const __attribute__((address_space(1))) void*)(unsigned long long)g,
        (__attribute__((address_space(3))) void*)(unsigned int)(unsigned long long)l,
        16, 0, 0);
}

// ---------------- embed + LN1 : one wave per (b,s) row, f32 in/out ----------------
__global__ __launch_bounds__(256) void embed_ln_k(
    const int* __restrict__ in_ex, const int* __restrict__ in_cat,
    const int* __restrict__ in_res, const float* __restrict__ in_pos,
    const float* __restrict__ E_res, const float* __restrict__ E_ex,
    const float* __restrict__ E_cat, const float* __restrict__ g,
    const float* __restrict__ be, float* __restrict__ out)
{
    int wave = threadIdx.x >> 6, lane = threadIdx.x & 63;
    int row = blockIdx.x * 4 + wave;          // < 16384
    int res = in_res[row];
    int ex  = in_ex[row] + 10000 * res;
    int cat = in_cat[row] + 300 * res;
    int d0 = lane * 8;
    const float* pr = &E_res[(size_t)res * DD + d0];
    const float* pe = &E_ex[(size_t)ex * DD + d0];
    const float* pc = &E_cat[(size_t)cat * DD + d0];
    const float* pp = &in_pos[(size_t)row * DD + d0];
    float x[8]; float s = 0.f;
    #pragma unroll
    for (int j = 0; j < 8; j++) { x[j] = pr[j] + pe[j] + pc[j] + pp[j]; s += x[j]; }
    s = wave_sum(s);
    float mean = s * (1.0f / DD);
    float vs = 0.f;
    #pragma unroll
    for (int j = 0; j < 8; j++) { float d = x[j] - mean; vs += d * d; }
    vs = wave_sum(vs);
    float rstd = rsqrtf(vs * (1.0f / DD) + 1e-5f);
    #pragma unroll
    for (int j = 0; j < 8; j++)
        out[(size_t)row * DD + d0 + j] = (x[j] - mean) * rstd * g[d0 + j] + be[d0 + j];
}

// ---------------- generic row LayerNorm: f32 in, f32 or bf16 out ----------------
template<bool OUTB>
__global__ __launch_bounds__(256) void ln_k(
    const float* __restrict__ x, const float* __restrict__ g,
    const float* __restrict__ be, void* __restrict__ outv)
{
    int wave = threadIdx.x >> 6, lane = threadIdx.x & 63;
    int row = blockIdx.x * 4 + wave;
    int d0 = lane * 8;
    const float* px = &x[(size_t)row * DD + d0];
    float xv[8]; float s = 0.f;
    #pragma unroll
    for (int j = 0; j < 8; j++) { xv[j] = px[j]; s += xv[j]; }
    s = wave_sum(s);
    float mean = s * (1.0f / DD);
    float vs = 0.f;
    #pragma unroll
    for (int j = 0; j < 8; j++) { float d = xv[j] - mean; vs += d * d; }
    vs = wave_sum(vs);
    float rstd = rsqrtf(vs * (1.0f / DD) + 1e-5f);
    #pragma unroll
    for (int j = 0; j < 8; j++) {
        float v = (xv[j] - mean) * rstd * g[d0 + j] + be[d0 + j];
        if (OUTB) ((u16*)outv)[(size_t)row * DD + d0 + j] = f2b(v);
        else      ((float*)outv)[(size_t)row * DD + d0 + j] = v;
    }
}

// ---------------- all-weight transpose + cast via LDS tiles ----------------
// f32 W[k][n] (512x512) -> bf16 Wt[n][k], 10 weights in one launch.
// Block = 64x64 tile: coalesced f32x4 reads, LDS stride-72 stage,
// coalesced u16x8 writes (replaces 10 scatter-write kernels).
struct W10 { const float* p[10]; };
__global__ __launch_bounds__(256) void transpose_all_k(W10 wp, u16* __restrict__ dst)
{
    __shared__ __align__(16) u16 T[64 * 72];
    int w = blockIdx.z;
    const float* src = wp.p[w];
    u16* d = dst + (size_t)w * 262144;
    int tk = blockIdx.x;          // k-tile 0..7
    int tn = blockIdx.y;          // n-tile 0..7
    int tid = threadIdx.x;
    {
        int r = tid >> 4;         // 0..15
        int c4 = (tid & 15) * 4;  // 0..60
        #pragma unroll
        for (int it = 0; it < 4; it++) {
            int kr = it * 16 + r;
            const float* s4 = &src[(size_t)(tk * 64 + kr) * 512 + tn * 64 + c4];
            f32x4 v = *(const f32x4*)s4;
            *(unsigned int*)&T[kr * 72 + c4]     = cvtpk(v[0], v[1]);
            *(unsigned int*)&T[kr * 72 + c4 + 2] = cvtpk(v[2], v[3]);
        }
    }
    __syncthreads();
    {
        int nn = tid >> 2;            // 0..63
        int k16 = (tid & 3) * 16;     // 0,16,32,48
        u16x8 a, b;
        #pragma unroll
        for (int j = 0; j < 8; j++) {
            a[j] = T[(k16 + j) * 72 + nn];
            b[j] = T[(k16 + 8 + j) * 72 + nn];
        }
        u16* o = &d[(size_t)(tn * 64 + nn) * 512 + tk * 64 + k16];
        *(u16x8*)&o[0] = a;
        *(u16x8*)&o[8] = b;
    }
}

// ---------------- V pyramid pool via LDS transpose ----------------
__global__ __launch_bounds__(256) void pool_vt_k(const u16* __restrict__ Vp, u16* __restrict__ VPt)
{
    __shared__ __align__(16) u16 T[64 * 72];   // local s x d, stride 72 (16B-aligned rows)
    int tid = threadIdx.x;
    int st = blockIdx.x;                        // 0..15 s-tile
    int h  = blockIdx.y;                        // 0..7
    int b  = blockIdx.z;                        // 0..15
    int s0 = st * 64;
    {
        const u16* src = &Vp[((size_t)(b * SS + s0)) * DD + h * DH];
        #pragma unroll
        for (int it = 0; it < 2; it++) {
            int idx = it * 256 + tid;           // 512 x 16B units
            int row = idx >> 3, unit = idx & 7;
            *(u16x8*)&T[row * 72 + unit * 8] =
                *(const u16x8*)&src[(size_t)row * DD + unit * 8];
        }
    }
    __syncthreads();
    int d = tid & 63, g = tid >> 6;             // 4 waves: g = 0..3
    size_t obase = ((size_t)(b * HH + h) * DH + d) * KTOT;
    // level 0: 64 keys at s0
    #pragma unroll
    for (int gg = 0; gg < 2; gg++) {
        int grp = g * 2 + gg;                   // s chunk of 8
        u16x8 v;
        #pragma unroll
        for (int j = 0; j < 8; j++) v[j] = T[(grp * 8 + j) * 72 + d];
        *(u16x8*)&VPt[obase + s0 + grp * 8] = v;
    }
    // level 1: 32 keys at 1024 + st*32
    {
        u16x8 v;
        #pragma unroll
        for (int j = 0; j < 8; j++) {
            int sl = g * 8 + j;                 // 0..31
            float a = b2f(T[(2 * sl) * 72 + d]) + b2f(T[(2 * sl + 1) * 72 + d]);
            v[j] = f2b(a * 0.5f);
        }
        *(u16x8*)&VPt[obase + 1024 + st * 32 + g * 8] = v;
    }
    // level 2: 16 keys at 1536 + st*16
    {
        u16x4 v;
        #pragma unroll
        for (int j = 0; j < 4; j++) {
            int s2 = g * 4 + j;                 // 0..15
            float a = 0.f;
            #pragma unroll
            for (int i = 0; i < 4; i++) a += b2f(T[(4 * s2 + i) * 72 + d]);
            v[j] = f2b(a * 0.25f);
        }
        *(u16x4*)&VPt[obase + 1536 + st * 16 + g * 4] = v;
    }
}

// ---------------- MFMA GEMM, double-buffered: C(M,512) = A @ W + bias [relu][+resid] ----------------
// Staging for tile t+1 is issued at the top of iteration t (global loads fly
// under the MFMA phase); one barrier per iteration drains them. bf16 operands
// use global_load_lds (linear stride-32 rows); f32 A goes global->VGPR during
// MFMA, then cvt_pk + ds_write into stride-40 rows (write-conflict-free).
// oscale multiplies (acc+bias) in the epilogue (pre-scales Q by 0.125*log2e).
// KLAY: write bf16 output permuted into KP layout (B,H,1792,64) level-0 region
// AND the level-1/2 pooled keys (pools are lane-local over acc rows quad*4+rr)
// -> replaces the separate pool_k12 kernel entirely.
template<bool AF32, bool RELU, bool RES, bool OUTB, bool KLAY>
__global__ __launch_bounds__(256) void gemm_k(
    const void* __restrict__ Av, const u16* __restrict__ Wt,
    const float* __restrict__ bias, const float* __restrict__ resid,
    void* __restrict__ Cv, int M, int K, float oscale)
{
    const int N = 512;
    constexpr int ASW = AF32 ? 40 : 32;
    __shared__ __align__(16) u16 As[2][128 * ASW];
    __shared__ __align__(16) u16 Bs[2][128 * 32];
    int tid = threadIdx.x;
    int wave = tid >> 6, lane = tid & 63;
    int quad = lane >> 4, l16 = lane & 15;
    int m0 = blockIdx.y * 128, n0 = blockIdx.x * 128;
    int wm = (wave >> 1) * 64, wn = (wave & 1) * 64;
    int r = tid >> 1, cg = (tid & 1) * 16;          // AF32 manual staging
    int grow = wave * 16 + (lane >> 2);             // gl16 row (64-row half)
    int gk = (lane & 3) * 8;                        // u16 offset (16B unit)
    const float* Af = (const float*)Av;
    const u16*  Ab = (const u16*)Av;
    f32x4 acc[4][4];
    #pragma unroll
    for (int i = 0; i < 4; i++)
        #pragma unroll
        for (int j = 0; j < 4; j++)
            #pragma unroll
            for (int rr = 0; rr < 4; rr++) acc[i][j][rr] = 0.f;

    const int NT = K >> 5;
    f32x4 s0, s1, s2, s3;                           // AF32 in-flight A regs

    #define ISSUE_B(t, buf) { int k0_ = (t) << 5; \
        gl16(&Wt[(size_t)(n0 + grow) * 512 + k0_ + gk],      &Bs[buf][grow * 32 + gk]); \
        gl16(&Wt[(size_t)(n0 + 64 + grow) * 512 + k0_ + gk], &Bs[buf][(64 + grow) * 32 + gk]); }
    #define ISSUE_A16(t, buf) { int k0_ = (t) << 5; \
        gl16(&Ab[(size_t)(m0 + grow) * K + k0_ + gk],      &As[buf][grow * 32 + gk]); \
        gl16(&Ab[(size_t)(m0 + 64 + grow) * K + k0_ + gk], &As[buf][(64 + grow) * 32 + gk]); }
    #define LOAD_A32(t) { const float* src_ = &Af[(size_t)(m0 + r) * K + ((t) << 5) + cg]; \
        s0 = *(const f32x4*)&src_[0];  s1 = *(const f32x4*)&src_[4]; \
        s2 = *(const f32x4*)&src_[8];  s3 = *(const f32x4*)&src_[12]; }
    #define WRITE_A32(buf) { union { unsigned int w[4]; u16x8 v; } L_, H_; \
        L_.w[0] = cvtpk(s0[0], s0[1]); L_.w[1] = cvtpk(s0[2], s0[3]); \
        L_.w[2] = cvtpk(s1[0], s1[1]); L_.w[3] = cvtpk(s1[2], s1[3]); \
        H_.w[0] = cvtpk(s2[0], s2[1]); H_.w[1] = cvtpk(s2[2], s2[3]); \
        H_.w[2] = cvtpk(s3[0], s3[1]); H_.w[3] = cvtpk(s3[2], s3[3]); \
        *(u16x8*)&As[buf][r * ASW + cg]     = L_.v; \
        *(u16x8*)&As[buf][r * ASW + cg + 8] = H_.v; }

    // prologue: stage tile 0 into buffer 0
    if (AF32) { LOAD_A32(0); WRITE_A32(0); }
    else      { ISSUE_A16(0, 0); }
    ISSUE_B(0, 0);
    __syncthreads();

    for (int t = 0; t < NT; ++t) {
        int cur = t & 1, nxt = cur ^ 1;
        if (t + 1 < NT) {
            if (AF32) { LOAD_A32(t + 1); }
            else      { ISSUE_A16(t + 1, nxt); }
            ISSUE_B(t + 1, nxt);
        }
        s16x8 af[4], bfr[4];
        #pragma unroll
        for (int i = 0; i < 4; i++)
            af[i] = u2s8(*(const u16x8*)&As[cur][(wm + i * 16 + l16) * ASW + quad * 8]);
        #pragma unroll
        for (int j = 0; j < 4; j++)
            bfr[j] = u2s8(*(const u16x8*)&Bs[cur][(wn + j * 16 + l16) * 32 + quad * 8]);
        #pragma unroll
        for (int i = 0; i < 4; i++)
            #pragma unroll
            for (int j = 0; j < 4; j++)
                acc[i][j] = mfma16(af[i], bfr[j], acc[i][j]);
        if (AF32 && t + 1 < NT) { WRITE_A32(nxt); }
        __syncthreads();
    }
    #undef ISSUE_B
    #undef ISSUE_A16
    #undef LOAD_A32
    #undef WRITE_A32

    #pragma unroll
    for (int j = 0; j < 4; j++) {
        int col = n0 + wn + j * 16 + l16;
        float bv = bias[col];
        #pragma unroll
        for (int i = 0; i < 4; i++) {
            int rowb = m0 + wm + i * 16 + quad * 4;
            if (KLAY) {
                float vv[4];
                #pragma unroll
                for (int rr = 0; rr < 4; rr++) vv[rr] = acc[i][j][rr] + bv;
                int b_ = rowb >> 10, s_ = rowb & 1023;      // s_ multiple of 4
                size_t bh = (size_t)(b_ * HH + (col >> 6)) * KTOT;
                int dd = col & 63;
                u16* C16 = (u16*)Cv;
                #pragma unroll
                for (int rr = 0; rr < 4; rr++)
                    C16[(bh + s_ + rr) * DH + dd] = f2b(vv[rr]);
                C16[(bh + 1024 + (s_ >> 1)) * DH + dd]     = f2b((vv[0] + vv[1]) * 0.5f);
                C16[(bh + 1024 + (s_ >> 1) + 1) * DH + dd] = f2b((vv[2] + vv[3]) * 0.5f);
                C16[(bh + 1536 + (s_ >> 2)) * DH + dd]     = f2b((vv[0] + vv[1] + vv[2] + vv[3]) * 0.25f);
            } else {
                #pragma unroll
                for (int rr = 0; rr < 4; rr++) {
                    float v = (acc[i][j][rr] + bv) * oscale;
                    if (RELU) v = fmaxf(v, 0.f);
                    int row = rowb + rr;
                    if (RES) v += resid[(size_t)row * N + col];
                    if (OUTB) ((u16*)Cv)[(size_t)row * N + col] = f2b(v);
                    else      ((float*)Cv)[(size_t)row * N + col] = v;
                }
            }
        }
    }
}

// ---------------- MFMA flash pyramid attention: 8-way q-split, 2 tiles/wave ----------------
// 1024 blocks x 256 threads (4 waves) -> 4 blocks/CU (LDS 4x40KB = 160KB),
// 16 waves/CU. Block owns (b,h) with an 8-way split x; wave-global index
// wg = x*4+wave handles tiles {wg, 63-wg} (constant work-sum). K/V LDS
// fragments are lane-indexed only: loaded once per chunk, shared by both
// q-streams. Double-buffered K/V LDS: one barrier per chunk; staging writes
// for chunk t+1 land after compute of t. Swapped QK (mfma(K,Q)) + sigma key
// permutation put scores directly in PV A-fragment order; Q pre-scaled by
// 0.125*log2e so p = exp2(z) with no online max (|z| << 1 by construction).
__global__ __launch_bounds__(256, 4) void attn_k(
    const u16* __restrict__ Qp, const u16* __restrict__ KP,
    const u16* __restrict__ VPt, u16* __restrict__ Hout)
{
    __shared__ __align__(16) u16 Ksh[2][64 * KSW];   // keys x dh
    __shared__ __align__(16) u16 Vsh[2][64 * KSW];   // dh x keys
    int tid = threadIdx.x;
    int wave = tid >> 6, lane = tid & 63;
    int quad = lane >> 4, l16 = lane & 15;
    // XCD-swizzled decode: id = (bh&7) + 8*(x + 8*(bh>>3))
    int id = blockIdx.x;
    int h = id & 7;
    int inner = id >> 3;
    int x = inner & 7, b = inner >> 3;

    int wg = x * 4 + wave;                 // 0..31
    int tiles[2] = { wg, 63 - wg };

    const u16* Kb = KP  + ((size_t)(b * HH + h)) * KTOT * DH;
    const u16* Vt = VPt + ((size_t)(b * HH + h)) * DH * KTOT;

    s16x8 qa[2][2];
    f32x4 o[2][4];
    float lrun[2];
    int q0a[2];
    #pragma unroll
    for (int c = 0; c < 2; c++) {
        int q0 = tiles[c] * 16;
        q0a[c] = q0;
        lrun[c] = 0.f;
        const u16* qrow = Qp + ((size_t)(b * SS + q0 + l16)) * DD + h * DH;
        qa[c][0] = u2s8(*(const u16x8*)&qrow[quad * 8]);
        qa[c][1] = u2s8(*(const u16x8*)&qrow[32 + quad * 8]);
        #pragma unroll
        for (int j = 0; j < 4; j++)
            #pragma unroll
            for (int rr = 0; rr < 4; rr++) o[c][j][rr] = 0.f;
    }

    // sigma row base for this lane (K-fragment row within chunk; t adds {0,4,32,36})
    int row0 = 8 * (l16 >> 2) + (l16 & 3);

    // staging: 2 passes of 256 consecutive 16B units per tensor
    int u0 = tid, u1 = 256 + tid;
    int kr0 = u0 >> 3, ku0 = (u0 & 7) * 8;
    int kr1 = u1 >> 3, ku1 = (u1 & 7) * 8;

    // prologue: load + stage chunk 0 into buf 0
    u16x8 kreg0 = *(const u16x8*)&Kb[(size_t)u0 * 8];
    u16x8 kreg1 = *(const u16x8*)&Kb[(size_t)u1 * 8];
    u16x8 vreg0 = *(const u16x8*)&Vt[(size_t)kr0 * KTOT + ku0];
    u16x8 vreg1 = *(const u16x8*)&Vt[(size_t)kr1 * KTOT + ku1];
    *(u16x8*)&Ksh[0][kr0 * KSW + ku0] = kreg0;
    *(u16x8*)&Ksh[0][kr1 * KSW + ku1] = kreg1;
    *(u16x8*)&Vsh[0][kr0 * KSW + ku0] = vreg0;
    *(u16x8*)&Vsh[0][kr1 * KSW + ku1] = vreg1;
    __syncthreads();

    for (int ch = 0; ch < 28; ch++) {
        int cur = ch & 1;
        int kbase = ch * 64;
        int lv = (ch < 16) ? 0 : (ch < 24) ? 1 : 2;
        if (ch + 1 < 28) {     // global prefetch for next chunk (lands during compute)
            int nb = (ch + 1) * 64;
            kreg0 = *(const u16x8*)&Kb[(size_t)nb * DH + u0 * 8];
            kreg1 = *(const u16x8*)&Kb[(size_t)nb * DH + u1 * 8];
            vreg0 = *(const u16x8*)&Vt[(size_t)kr0 * KTOT + nb + ku0];
            vreg1 = *(const u16x8*)&Vt[(size_t)kr1 * KTOT + nb + ku1];
        }

        int efirst = (lv == 0) ? kbase
                   : (lv == 1) ? 2 * (kbase - 1024) + 1
                               : 4 * (kbase - 1536) + 3;
        int elast  = (lv == 0) ? kbase + 63
                   : (lv == 1) ? 2 * (kbase + 63 - 1024) + 1
                               : 4 * (kbase + 63 - 1536) + 3;
        bool act[2];
        #pragma unroll
        for (int c = 0; c < 2; c++) act[c] = (efirst <= q0a[c] + 15);

        if (act[0] | act[1]) {
            // K fragments: once per chunk, shared by both active c
            s16x8 fA[4], fB[4];
            #pragma unroll
            for (int t = 0; t < 4; t++) {
                const int toff = (t & 1) * 4 + (t >> 1) * 32;
                const u16* kr = &Ksh[cur][(row0 + toff) * KSW];
                fA[t] = u2s8(*(const u16x8*)&kr[quad * 8]);
                fB[t] = u2s8(*(const u16x8*)&kr[32 + quad * 8]);
            }
            s16x8 pfa[2], pfb[2];
            #pragma unroll
            for (int c = 0; c < 2; c++) {
                if (!act[c]) continue;
                // QK^T swapped: D[key][q]; kk(t,quad,rr) = toff(t) + 8*quad + rr
                f32x4 zt[4];
                __builtin_amdgcn_s_setprio(1);
                #pragma unroll
                for (int t = 0; t < 4; t++) {
                    f32x4 z;
                    #pragma unroll
                    for (int rr = 0; rr < 4; rr++) z[rr] = 0.f;
                    z = mfma16(fA[t], qa[c][0], z);
                    zt[t] = mfma16(fB[t], qa[c][1], z);
                }
                __builtin_amdgcn_s_setprio(0);

                if (elast > q0a[c]) {      // partial chunk: causal mask
                    int q = q0a[c] + l16;
                    int kmaxv = (lv == 0) ? q - kbase
                              : (lv == 1) ? ((q - 1) >> 1) - (kbase - 1024)
                                          : ((q - 3) >> 2) - (kbase - 1536);
                    int thrb = kmaxv - 8 * quad;
                    #pragma unroll
                    for (int t = 0; t < 4; t++) {
                        int thr = thrb - ((t & 1) * 4 + (t >> 1) * 32);
                        #pragma unroll
                        for (int rr = 0; rr < 4; rr++)
                            if (rr > thr) zt[t][rr] = -1e30f;
                    }
                }

                // softmax numerator: p = exp2(z) directly (pre-scaled, no max)
                float p[4][4]; float ps0 = 0.f, ps1 = 0.f;
                #pragma unroll
                for (int t = 0; t < 4; t++)
                    #pragma unroll
                    for (int rr = 0; rr < 4; rr++) {
                        p[t][rr] = exp2a(zt[t][rr]);
                        if (t & 1) ps1 += p[t][rr]; else ps0 += p[t][rr];
                    }
                float ps = ps0 + ps1;
                ps += __shfl_xor(ps, 16, 64);
                ps += __shfl_xor(ps, 32, 64);
                lrun[c] += ps;

                union { unsigned int w[4]; u16x8 v; } U0, U1;
                U0.w[0] = cvtpk(p[0][0], p[0][1]); U0.w[1] = cvtpk(p[0][2], p[0][3]);
                U0.w[2] = cvtpk(p[1][0], p[1][1]); U0.w[3] = cvtpk(p[1][2], p[1][3]);
                U1.w[0] = cvtpk(p[2][0], p[2][1]); U1.w[1] = cvtpk(p[2][2], p[2][3]);
                U1.w[2] = cvtpk(p[3][0], p[3][1]); U1.w[3] = cvtpk(p[3][2], p[3][3]);
                pfa[c] = u2s8(U0.v); pfb[c] = u2s8(U1.v);
            }

            // V fragments: once per chunk, shared by both active c
            s16x8 vA[4], vB[4];
            #pragma unroll
            for (int j = 0; j < 4; j++) {
                const u16* vr = &Vsh[cur][(j * 16 + l16) * KSW];
                vA[j] = u2s8(*(const u16x8*)&vr[quad * 8]);
                vB[j] = u2s8(*(const u16x8*)&vr[32 + quad * 8]);
            }
            __builtin_amdgcn_s_setprio(1);
            #pragma unroll
            for (int c = 0; c < 2; c++) {
                if (!act[c]) continue;
                #pragma unroll
                for (int j = 0; j < 4; j++) {
                    o[c][j] = mfma16(pfa[c], vA[j], o[c][j]);
                    o[c][j] = mfma16(pfb[c], vB[j], o[c][j]);
                }
            }
            __builtin_amdgcn_s_setprio(0);
        }

        if (ch + 1 < 28) {     // stage next chunk into the other buffer
            int nxt = cur ^ 1;
            *(u16x8*)&Ksh[nxt][kr0 * KSW + ku0] = kreg0;
            *(u16x8*)&Ksh[nxt][kr1 * KSW + ku1] = kreg1;
            *(u16x8*)&Vsh[nxt][kr0 * KSW + ku0] = vreg0;
            *(u16x8*)&Vsh[nxt][kr1 * KSW + ku1] = vreg1;
        }
        __syncthreads();
    }

    // epilogue per tile
    #pragma unroll
    for (int c = 0; c < 2; c++) {
        float il = 1.0f / lrun[c];
        float ilr[4];
        #pragma unroll
        for (int rr = 0; rr < 4; rr++) ilr[rr] = __shfl(il, quad * 4 + rr, 64);
        #pragma unroll
        for (int rr = 0; rr < 4; rr++) {
            int q = q0a[c] + quad * 4 + rr;
            #pragma unroll
            for (int j = 0; j < 4; j++)
                Hout[((size_t)(b * SS + q)) * DD + h * DH + j * 16 + l16] = f2b(o[c][j][rr] * ilr[rr]);
        }
    }
}

extern "C" void kernel_launch(void* const* d_in, const int* in_sizes, int n_in,
                              void* d_out, int out_size, void* d_ws, size_t ws_size,
                              hipStream_t stream)
{
    (void)in_sizes; (void)n_in; (void)out_size; (void)ws_size;
    const int* in_ex  = (const int*)d_in[0];
    const int* in_cat = (const int*)d_in[1];
    const int* in_res = (const int*)d_in[2];
    const float* in_pos = (const float*)d_in[3];
    const float* en_out = (const float*)d_in[4];
    const float* E_res  = (const float*)d_in[5];
    const float* E_ex   = (const float*)d_in[6];
    const float* E_cat  = (const float*)d_in[7];
    const float* g1 = (const float*)d_in[8],  *be1 = (const float*)d_in[9];
    const float* g2 = (const float*)d_in[10], *be2 = (const float*)d_in[11];
    const float* g3 = (const float*)d_in[12], *be3 = (const float*)d_in[13];
    const float* Wq1 = (const float*)d_in[14], *bq1 = (const float*)d_in[15];
    const float* Wk1 = (const float*)d_in[16], *bk1 = (const float*)d_in[17];
    const float* Wv1 = (const float*)d_in[18], *bv1 = (const float*)d_in[19];
    const float* Wo1 = (const float*)d_in[20], *bo1 = (const float*)d_in[21];
    const float* Wq2 = (const float*)d_in[22], *bq2 = (const float*)d_in[23];
    const float* Wk2 = (const float*)d_in[24], *bk2 = (const float*)d_in[25];
    const float* Wv2 = (const float*)d_in[26], *bv2 = (const float*)d_in[27];
    const float* Wo2 = (const float*)d_in[28], *bo2 = (const float*)d_in[29];
    const float* fW1 = (const float*)d_in[30], *fb1 = (const float*)d_in[31];
    const float* fW2 = (const float*)d_in[32], *fb2 = (const float*)d_in[33];

    char* ws = (char*)d_ws;
    const size_t U = (size_t)NROW * DD * 2;        // 16.78 MB
    float* x1 = (float*)(ws);                      // 2U f32  [ph4: en bf16 in 1st U; then x3 f32]
    u16* qb   = (u16*)(ws + 2 * U);                // 1U
    u16* vb   = (u16*)(ws + 3 * U);                // 1U
    u16* hb   = (u16*)(ws + 4 * U);                // 1U  [ph5: ff1]
    u16* kp   = (u16*)(ws + 5 * U);                // 1.75U (B,H,1792,64)
    u16* vpt  = (u16*)(ws + 5 * U + 7 * U / 4);    // 1.75U (B,H,64,1792)
    u16* wt   = (u16*)(ws + 8 * U + U / 2);        // 10 x 512KB bf16 transposed weights
    float* x2 = (float*)d_out;                     // d_out doubles as x2 (fully overwritten at end)
    u16* en = (u16*)(ws);                          // phase-4 alias of dead x1 slot
    float* x3 = x1;                                // phase-4 output slot
    float* x4 = (float*)(ws + 5 * U);              // phase-5 alias over kp/vpt (dead)
    u16* ff1 = hb;                                 // phase-5 alias

    W10 wp;
    const float* wsrc[10] = {Wq1, Wk1, Wv1, Wo1, Wq2, Wk2, Wv2, Wo2, fW1, fW2};
    for (int i = 0; i < 10; i++) wp.p[i] = wsrc[i];
    transpose_all_k<<<dim3(8, 8, 10), 256, 0, stream>>>(wp, wt);
    u16* tWq1 = wt,            *tWk1 = wt + 262144,   *tWv1 = wt + 2*262144, *tWo1 = wt + 3*262144;
    u16* tWq2 = wt + 4*262144, *tWk2 = wt + 5*262144, *tWv2 = wt + 6*262144, *tWo2 = wt + 7*262144;
    u16* tF1  = wt + 8*262144, *tF2  = wt + 9*262144;

    dim3 ggrid(4, 128);
    dim3 vtgrid(16, 8, 16);
    const float QSC = 0.18033688f;   // 0.125 * log2(e): folded into Q projection

    // phase 2: x1 = LN1(embed sum)   (f32)
    embed_ln_k<<<4096, 256, 0, stream>>>(in_ex, in_cat, in_res, in_pos,
                                         E_res, E_ex, E_cat, g1, be1, x1);

    // phase 3: self-attention; x2 = x1 + attn(x1) @ Wo1
    gemm_k<true,false,false,true,false><<<ggrid, 256, 0, stream>>>(x1, tWq1, bq1, nullptr, qb, NROW, 512, QSC);
    gemm_k<true,false,false,true,true ><<<ggrid, 256, 0, stream>>>(x1, tWk1, bk1, nullptr, kp, NROW, 512, 1.0f);
    gemm_k<true,false,false,true,false><<<ggrid, 256, 0, stream>>>(x1, tWv1, bv1, nullptr, vb, NROW, 512, 1.0f);
    pool_vt_k<<<vtgrid, 256, 0, stream>>>(vb, vpt);
    attn_k<<<1024, 256, 0, stream>>>(qb, kp, vpt, hb);
    gemm_k<false,false,true,false,false><<<ggrid, 256, 0, stream>>>(hb, tWo1, bo1, x1, x2, NROW, 512, 1.0f);

    // phase 4: cross-attention; x3 = x2 + attn(q=x2, kv=en) @ Wo2
    ln_k<true><<<4096, 256, 0, stream>>>(en_out, g2, be2, en);
    gemm_k<true,false,false,true,false><<<ggrid, 256, 0, stream>>>(x2, tWq2, bq2, nullptr, qb, NROW, 512, QSC);
    gemm_k<false,false,false,true,true ><<<ggrid, 256, 0, stream>>>(en, tWk2, bk2, nullptr, kp, NROW, 512, 1.0f);
    gemm_k<false,false,false,true,false><<<ggrid, 256, 0, stream>>>(en, tWv2, bv2, nullptr, vb, NROW, 512, 1.0f);
    pool_vt_k<<<vtgrid, 256, 0, stream>>>(vb, vpt);
    attn_k<<<1024, 256, 0, stream>>>(qb, kp, vpt, hb);
    gemm_k<false,false,true,false,false><<<ggrid, 256, 0, stream>>>(hb, tWo2, bo2, x2, x3, NROW, 512, 1.0f);

    // phase 5: x4 = LN3(x3); out = x4 + relu(x4@fW1+fb1)@fW2+fb2
    ln_k<false><<<4096, 256, 0, stream>>>(x3, g3, be3, x4);
    gemm_k<true,true,false,true,false><<<ggrid, 256, 0, stream>>>(x4, tF1, fb1, nullptr, ff1, NROW, 512, 1.0f);
    gemm_k<false,false,true,false,false><<<ggrid, 256, 0, stream>>>(ff1, tF2, fb2, x4, (float*)d_out, NROW, 512, 1.0f);
}

// Round 7
// 638.501 us; speedup vs baseline: 1.1115x; 1.1115x over previous
//
#include <hip/hip_runtime.h>

// Decoder block, MI355X gfx950. ALL float tensors f32 (per reference); ints
// int32; output f32. GEMMs + attention use bf16 MFMA internally, f32
// accumulate; residual stream kept in f32.

#define BB 16
#define SS 1024
#define DD 512
#define HH 8
#define DH 64
#define KTOT 1792          // 1024 + 512 + 256 pyramid keys
#define NROW (BB*SS)       // 16384
#define KSW 80             // attn LDS row stride (u16): 40 dwords == 8 mod 32 -> conflict-free

typedef unsigned short u16;
typedef __attribute__((ext_vector_type(8))) u16 u16x8;
typedef __attribute__((ext_vector_type(4))) u16 u16x4;
typedef __attribute__((ext_vector_type(8))) short s16x8;
typedef __attribute__((ext_vector_type(4))) float f32x4;

__device__ __forceinline__ float b2f(u16 u) {
    return __uint_as_float(((unsigned int)u) << 16);
}
__device__ __forceinline__ u16 f2b(float f) {
    unsigned int u = __float_as_uint(f);
    return (u16)((u + 0x7FFF + ((u >> 16) & 1)) >> 16);
}
__device__ __forceinline__ s16x8 u2s8(u16x8 u) {
    union { u16x8 u; s16x8 s; } x; x.u = u; return x.s;
}
__device__ __forceinline__ f32x4 mfma16(s16x8 a, s16x8 b, f32x4 c) {
    return __builtin_amdgcn_mfma_f32_16x16x32_bf16(a, b, c, 0, 0, 0);
}
__device__ __forceinline__ float wave_sum(float v) {
    #pragma unroll
    for (int m = 1; m < 64; m <<= 1) v += __shfl_xor(v, m, 64);
    return v;
}
// native 2^x
__device__ __forceinline__ float exp2a(float x) {
    float r;
    asm("v_exp_f32 %0, %1" : "=v"(r) : "v"(x));
    return r;
}
// packed bf16 convert (RNE): low16 = bf16(a), high16 = bf16(b)
__device__ __forceinline__ unsigned int cvtpk(float a, float b) {
    unsigned int r;
    asm("v_cvt_pk_bf16_f32 %0, %1, %2" : "=v"(r) : "v"(a), "v"(b));
    return r;
}
// async global->LDS 16B: per-lane global addr, LDS dest = wave-uniform base + lane*16
__device__ __forceinline__ void gl16(const void* g, void* l) {
    __builtin_amdgcn_global_load_lds(
        (const __attribute__((address_space(1))) void*)(unsigned long long)g,
        (__attribute__((address_space(3))) void*)(unsigned int)(unsigned long long)l,
        16, 0, 0);
}

// ---------------- embed + LN1 : one wave per (b,s) row, f32 in/out ----------------
__global__ __launch_bounds__(256) void embed_ln_k(
    const int* __restrict__ in_ex, const int* __restrict__ in_cat,
    const int* __restrict__ in_res, const float* __restrict__ in_pos,
    const float* __restrict__ E_res, const float* __restrict__ E_ex,
    const float* __restrict__ E_cat, const float* __restrict__ g,
    const float* __restrict__ be, float* __restrict__ out)
{
    int wave = threadIdx.x >> 6, lane = threadIdx.x & 63;
    int row = blockIdx.x * 4 + wave;          // < 16384
    int res = in_res[row];
    int ex  = in_ex[row] + 10000 * res;
    int cat = in_cat[row] + 300 * res;
    int d0 = lane * 8;
    const float* pr = &E_res[(size_t)res * DD + d0];
    const float* pe = &E_ex[(size_t)ex * DD + d0];
    const float* pc = &E_cat[(size_t)cat * DD + d0];
    const float* pp = &in_pos[(size_t)row * DD + d0];
    float x[8]; float s = 0.f;
    #pragma unroll
    for (int j = 0; j < 8; j++) { x[j] = pr[j] + pe[j] + pc[j] + pp[j]; s += x[j]; }
    s = wave_sum(s);
    float mean = s * (1.0f / DD);
    float vs = 0.f;
    #pragma unroll
    for (int j = 0; j < 8; j++) { float d = x[j] - mean; vs += d * d; }
    vs = wave_sum(vs);
    float rstd = rsqrtf(vs * (1.0f / DD) + 1e-5f);
    #pragma unroll
    for (int j = 0; j < 8; j++)
        out[(size_t)row * DD + d0 + j] = (x[j] - mean) * rstd * g[d0 + j] + be[d0 + j];
}

// ---------------- generic row LayerNorm: f32 in, f32 or bf16 out ----------------
template<bool OUTB>
__global__ __launch_bounds__(256) void ln_k(
    const float* __restrict__ x, const float* __restrict__ g,
    const float* __restrict__ be, void* __restrict__ outv)
{
    int wave = threadIdx.x >> 6, lane = threadIdx.x & 63;
    int row = blockIdx.x * 4 + wave;
    int d0 = lane * 8;
    const float* px = &x[(size_t)row * DD + d0];
    float xv[8]; float s = 0.f;
    #pragma unroll
    for (int j = 0; j < 8; j++) { xv[j] = px[j]; s += xv[j]; }
    s = wave_sum(s);
    float mean = s * (1.0f / DD);
    float vs = 0.f;
    #pragma unroll
    for (int j = 0; j < 8; j++) { float d = xv[j] - mean; vs += d * d; }
    vs = wave_sum(vs);
    float rstd = rsqrtf(vs * (1.0f / DD) + 1e-5f);
    #pragma unroll
    for (int j = 0; j < 8; j++) {
        float v = (xv[j] - mean) * rstd * g[d0 + j] + be[d0 + j];
        if (OUTB) ((u16*)outv)[(size_t)row * DD + d0 + j] = f2b(v);
        else      ((float*)outv)[(size_t)row * DD + d0 + j] = v;
    }
}

// ---------------- all-weight transpose + cast via LDS tiles ----------------
// f32 W[k][n] (512x512) -> bf16 Wt[n][k], 10 weights in one launch.
struct W10 { const float* p[10]; };
__global__ __launch_bounds__(256) void transpose_all_k(W10 wp, u16* __restrict__ dst)
{
    __shared__ __align__(16) u16 T[64 * 72];
    int w = blockIdx.z;
    const float* src = wp.p[w];
    u16* d = dst + (size_t)w * 262144;
    int tk = blockIdx.x;          // k-tile 0..7
    int tn = blockIdx.y;          // n-tile 0..7
    int tid = threadIdx.x;
    {
        int r = tid >> 4;         // 0..15
        int c4 = (tid & 15) * 4;  // 0..60
        #pragma unroll
        for (int it = 0; it < 4; it++) {
            int kr = it * 16 + r;
            const float* s4 = &src[(size_t)(tk * 64 + kr) * 512 + tn * 64 + c4];
            f32x4 v = *(const f32x4*)s4;
            *(unsigned int*)&T[kr * 72 + c4]     = cvtpk(v[0], v[1]);
            *(unsigned int*)&T[kr * 72 + c4 + 2] = cvtpk(v[2], v[3]);
        }
    }
    __syncthreads();
    {
        int nn = tid >> 2;            // 0..63
        int k16 = (tid & 3) * 16;     // 0,16,32,48
        u16x8 a, b;
        #pragma unroll
        for (int j = 0; j < 8; j++) {
            a[j] = T[(k16 + j) * 72 + nn];
            b[j] = T[(k16 + 8 + j) * 72 + nn];
        }
        u16* o = &d[(size_t)(tn * 64 + nn) * 512 + tk * 64 + k16];
        *(u16x8*)&o[0] = a;
        *(u16x8*)&o[8] = b;
    }
}

// ---------------- V pyramid pool via LDS transpose ----------------
__global__ __launch_bounds__(256) void pool_vt_k(const u16* __restrict__ Vp, u16* __restrict__ VPt)
{
    __shared__ __align__(16) u16 T[64 * 72];   // local s x d, stride 72 (16B-aligned rows)
    int tid = threadIdx.x;
    int st = blockIdx.x;                        // 0..15 s-tile
    int h  = blockIdx.y;                        // 0..7
    int b  = blockIdx.z;                        // 0..15
    int s0 = st * 64;
    {
        const u16* src = &Vp[((size_t)(b * SS + s0)) * DD + h * DH];
        #pragma unroll
        for (int it = 0; it < 2; it++) {
            int idx = it * 256 + tid;           // 512 x 16B units
            int row = idx >> 3, unit = idx & 7;
            *(u16x8*)&T[row * 72 + unit * 8] =
                *(const u16x8*)&src[(size_t)row * DD + unit * 8];
        }
    }
    __syncthreads();
    int d = tid & 63, g = tid >> 6;             // 4 waves: g = 0..3
    size_t obase = ((size_t)(b * HH + h) * DH + d) * KTOT;
    // level 0: 64 keys at s0
    #pragma unroll
    for (int gg = 0; gg < 2; gg++) {
        int grp = g * 2 + gg;                   // s chunk of 8
        u16x8 v;
        #pragma unroll
        for (int j = 0; j < 8; j++) v[j] = T[(grp * 8 + j) * 72 + d];
        *(u16x8*)&VPt[obase + s0 + grp * 8] = v;
    }
    // level 1: 32 keys at 1024 + st*32
    {
        u16x8 v;
        #pragma unroll
        for (int j = 0; j < 8; j++) {
            int sl = g * 8 + j;                 // 0..31
            float a = b2f(T[(2 * sl) * 72 + d]) + b2f(T[(2 * sl + 1) * 72 + d]);
            v[j] = f2b(a * 0.5f);
        }
        *(u16x8*)&VPt[obase + 1024 + st * 32 + g * 8] = v;
    }
    // level 2: 16 keys at 1536 + st*16
    {
        u16x4 v;
        #pragma unroll
        for (int j = 0; j < 4; j++) {
            int s2 = g * 4 + j;                 // 0..15
            float a = 0.f;
            #pragma unroll
            for (int i = 0; i < 4; i++) a += b2f(T[(4 * s2 + i) * 72 + d]);
            v[j] = f2b(a * 0.25f);
        }
        *(u16x4*)&VPt[obase + 1536 + st * 16 + g * 4] = v;
    }
}

// ---------------- MFMA GEMM, double-buffered: C(M,512) = A @ W + bias [relu][+resid] ----------------
// KLAY: write bf16 output permuted into KP layout (B,H,1792,64) level-0 region
// AND the level-1/2 pooled keys (pools are lane-local over acc rows quad*4+rr).
template<bool AF32, bool RELU, bool RES, bool OUTB, bool KLAY>
__global__ __launch_bounds__(256) void gemm_k(
    const void* __restrict__ Av, const u16* __restrict__ Wt,
    const float* __restrict__ bias, const float* __restrict__ resid,
    void* __restrict__ Cv, int M, int K, float oscale)
{
    const int N = 512;
    constexpr int ASW = AF32 ? 40 : 32;
    __shared__ __align__(16) u16 As[2][128 * ASW];
    __shared__ __align__(16) u16 Bs[2][128 * 32];
    int tid = threadIdx.x;
    int wave = tid >> 6, lane = tid & 63;
    int quad = lane >> 4, l16 = lane & 15;
    int m0 = blockIdx.y * 128, n0 = blockIdx.x * 128;
    int wm = (wave >> 1) * 64, wn = (wave & 1) * 64;
    int r = tid >> 1, cg = (tid & 1) * 16;          // AF32 manual staging
    int grow = wave * 16 + (lane >> 2);             // gl16 row (64-row half)
    int gk = (lane & 3) * 8;                        // u16 offset (16B unit)
    const float* Af = (const float*)Av;
    const u16*  Ab = (const u16*)Av;
    f32x4 acc[4][4];
    #pragma unroll
    for (int i = 0; i < 4; i++)
        #pragma unroll
        for (int j = 0; j < 4; j++)
            #pragma unroll
            for (int rr = 0; rr < 4; rr++) acc[i][j][rr] = 0.f;

    const int NT = K >> 5;
    f32x4 s0, s1, s2, s3;                           // AF32 in-flight A regs

    #define ISSUE_B(t, buf) { int k0_ = (t) << 5; \
        gl16(&Wt[(size_t)(n0 + grow) * 512 + k0_ + gk],      &Bs[buf][grow * 32 + gk]); \
        gl16(&Wt[(size_t)(n0 + 64 + grow) * 512 + k0_ + gk], &Bs[buf][(64 + grow) * 32 + gk]); }
    #define ISSUE_A16(t, buf) { int k0_ = (t) << 5; \
        gl16(&Ab[(size_t)(m0 + grow) * K + k0_ + gk],      &As[buf][grow * 32 + gk]); \
        gl16(&Ab[(size_t)(m0 + 64 + grow) * K + k0_ + gk], &As[buf][(64 + grow) * 32 + gk]); }
    #define LOAD_A32(t) { const float* src_ = &Af[(size_t)(m0 + r) * K + ((t) << 5) + cg]; \
        s0 = *(const f32x4*)&src_[0];  s1 = *(const f32x4*)&src_[4]; \
        s2 = *(const f32x4*)&src_[8];  s3 = *(const f32x4*)&src_[12]; }
    #define WRITE_A32(buf) { union { unsigned int w[4]; u16x8 v; } L_, H_; \
        L_.w[0] = cvtpk(s0[0], s0[1]); L_.w[1] = cvtpk(s0[2], s0[3]); \
        L_.w[2] = cvtpk(s1[0], s1[1]); L_.w[3] = cvtpk(s1[2], s1[3]); \
        H_.w[0] = cvtpk(s2[0], s2[1]); H_.w[1] = cvtpk(s2[2], s2[3]); \
        H_.w[2] = cvtpk(s3[0], s3[1]); H_.w[3] = cvtpk(s3[2], s3[3]); \
        *(u16x8*)&As[buf][r * ASW + cg]     = L_.v; \
        *(u16x8*)&As[buf][r * ASW + cg + 8] = H_.v; }

    // prologue: stage tile 0 into buffer 0
    if (AF32) { LOAD_A32(0); WRITE_A32(0); }
    else      { ISSUE_A16(0, 0); }
    ISSUE_B(0, 0);
    __syncthreads();

    for (int t = 0; t < NT; ++t) {
        int cur = t & 1, nxt = cur ^ 1;
        if (t + 1 < NT) {
            if (AF32) { LOAD_A32(t + 1); }
            else      { ISSUE_A16(t + 1, nxt); }
            ISSUE_B(t + 1, nxt);
        }
        s16x8 af[4], bfr[4];
        #pragma unroll
        for (int i = 0; i < 4; i++)
            af[i] = u2s8(*(const u16x8*)&As[cur][(wm + i * 16 + l16) * ASW + quad * 8]);
        #pragma unroll
        for (int j = 0; j < 4; j++)
            bfr[j] = u2s8(*(const u16x8*)&Bs[cur][(wn + j * 16 + l16) * 32 + quad * 8]);
        #pragma unroll
        for (int i = 0; i < 4; i++)
            #pragma unroll
            for (int j = 0; j < 4; j++)
                acc[i][j] = mfma16(af[i], bfr[j], acc[i][j]);
        if (AF32 && t + 1 < NT) { WRITE_A32(nxt); }
        __syncthreads();
    }
    #undef ISSUE_B
    #undef ISSUE_A16
    #undef LOAD_A32
    #undef WRITE_A32

    #pragma unroll
    for (int j = 0; j < 4; j++) {
        int col = n0 + wn + j * 16 + l16;
        float bv = bias[col];
        #pragma unroll
        for (int i = 0; i < 4; i++) {
            int rowb = m0 + wm + i * 16 + quad * 4;
            if (KLAY) {
                float vv[4];
                #pragma unroll
                for (int rr = 0; rr < 4; rr++) vv[rr] = acc[i][j][rr] + bv;
                int b_ = rowb >> 10, s_ = rowb & 1023;      // s_ multiple of 4
                size_t bh = (size_t)(b_ * HH + (col >> 6)) * KTOT;
                int dd = col & 63;
                u16* C16 = (u16*)Cv;
                #pragma unroll
                for (int rr = 0; rr < 4; rr++)
                    C16[(bh + s_ + rr) * DH + dd] = f2b(vv[rr]);
                C16[(bh + 1024 + (s_ >> 1)) * DH + dd]     = f2b((vv[0] + vv[1]) * 0.5f);
                C16[(bh + 1024 + (s_ >> 1) + 1) * DH + dd] = f2b((vv[2] + vv[3]) * 0.5f);
                C16[(bh + 1536 + (s_ >> 2)) * DH + dd]     = f2b((vv[0] + vv[1] + vv[2] + vv[3]) * 0.25f);
            } else {
                #pragma unroll
                for (int rr = 0; rr < 4; rr++) {
                    float v = (acc[i][j][rr] + bv) * oscale;
                    if (RELU) v = fmaxf(v, 0.f);
                    int row = rowb + rr;
                    if (RES) v += resid[(size_t)row * N + col];
                    if (OUTB) ((u16*)Cv)[(size_t)row * N + col] = f2b(v);
                    else      ((float*)Cv)[(size_t)row * N + col] = v;
                }
            }
        }
    }
}

// ---------------- MFMA flash pyramid attention: 8-way q-split, 2 tiles/wave ----------------
// 1024 blocks x 256 threads (4 waves). Block owns (b,h) with an 8-way split x;
// wave-global index wg = x*4+wave handles tiles {wg, 63-wg}. K/V LDS fragments
// are lane-indexed only: loaded once per chunk, shared by both q-streams.
// Register-lean loop structure (NO launch_bounds min-waves clause -- round 5's
// (256,4) cap caused catastrophic scratch spills, WRITE_SIZE 16MB->244MB):
// QK is t-outer (K fragments live 8 regs at a time, zt[2][4] persists), PV is
// j-outer (V fragments live 8 regs at a time). Double-buffered K/V LDS, one
// barrier per chunk. Swapped QK (mfma(K,Q)) + sigma key permutation put scores
// directly in PV A-fragment order; Q pre-scaled by 0.125*log2e so p = exp2(z)
// with no online max (|z| << 1 by construction).
__global__ __launch_bounds__(256) void attn_k(
    const u16* __restrict__ Qp, const u16* __restrict__ KP,
    const u16* __restrict__ VPt, u16* __restrict__ Hout)
{
    __shared__ __align__(16) u16 Ksh[2][64 * KSW];   // keys x dh
    __shared__ __align__(16) u16 Vsh[2][64 * KSW];   // dh x keys
    int tid = threadIdx.x;
    int wave = tid >> 6, lane = tid & 63;
    int quad = lane >> 4, l16 = lane & 15;
    // XCD-swizzled decode: id = (bh&7) + 8*(x + 8*(bh>>3))
    int id = blockIdx.x;
    int h = id & 7;
    int inner = id >> 3;
    int x = inner & 7, b = inner >> 3;

    int wg = x * 4 + wave;                 // 0..31
    int tiles[2] = { wg, 63 - wg };

    const u16* Kb = KP  + ((size_t)(b * HH + h)) * KTOT * DH;
    const u16* Vt = VPt + ((size_t)(b * HH + h)) * DH * KTOT;

    s16x8 qa[2][2];
    f32x4 o[2][4];
    float lrun[2];
    int q0a[2];
    #pragma unroll
    for (int c = 0; c < 2; c++) {
        int q0 = tiles[c] * 16;
        q0a[c] = q0;
        lrun[c] = 0.f;
        const u16* qrow = Qp + ((size_t)(b * SS + q0 + l16)) * DD + h * DH;
        qa[c][0] = u2s8(*(const u16x8*)&qrow[quad * 8]);
        qa[c][1] = u2s8(*(const u16x8*)&qrow[32 + quad * 8]);
        #pragma unroll
        for (int j = 0; j < 4; j++)
            #pragma unroll
            for (int rr = 0; rr < 4; rr++) o[c][j][rr] = 0.f;
    }

    // sigma row base for this lane (K-fragment row within chunk; t adds {0,4,32,36})
    int row0 = 8 * (l16 >> 2) + (l16 & 3);

    // staging: 2 passes of 256 consecutive 16B units per tensor
    int u0 = tid, u1 = 256 + tid;
    int kr0 = u0 >> 3, ku0 = (u0 & 7) * 8;
    int kr1 = u1 >> 3, ku1 = (u1 & 7) * 8;

    // prologue: load + stage chunk 0 into buf 0
    u16x8 kreg0 = *(const u16x8*)&Kb[(size_t)u0 * 8];
    u16x8 kreg1 = *(const u16x8*)&Kb[(size_t)u1 * 8];
    u16x8 vreg0 = *(const u16x8*)&Vt[(size_t)kr0 * KTOT + ku0];
    u16x8 vreg1 = *(const u16x8*)&Vt[(size_t)kr1 * KTOT + ku1];
    *(u16x8*)&Ksh[0][kr0 * KSW + ku0] = kreg0;
    *(u16x8*)&Ksh[0][kr1 * KSW + ku1] = kreg1;
    *(u16x8*)&Vsh[0][kr0 * KSW + ku0] = vreg0;
    *(u16x8*)&Vsh[0][kr1 * KSW + ku1] = vreg1;
    __syncthreads();

    for (int ch = 0; ch < 28; ch++) {
        int cur = ch & 1;
        int kbase = ch * 64;
        int lv = (ch < 16) ? 0 : (ch < 24) ? 1 : 2;
        if (ch + 1 < 28) {     // global prefetch for next chunk (lands during compute)
            int nb = (ch + 1) * 64;
            kreg0 = *(const u16x8*)&Kb[(size_t)nb * DH + u0 * 8];
            kreg1 = *(const u16x8*)&Kb[(size_t)nb * DH + u1 * 8];
            vreg0 = *(const u16x8*)&Vt[(size_t)kr0 * KTOT + nb + ku0];
            vreg1 = *(const u16x8*)&Vt[(size_t)kr1 * KTOT + nb + ku1];
        }

        int efirst = (lv == 0) ? kbase
                   : (lv == 1) ? 2 * (kbase - 1024) + 1
                               : 4 * (kbase - 1536) + 3;
        int elast  = (lv == 0) ? kbase + 63
                   : (lv == 1) ? 2 * (kbase + 63 - 1024) + 1
                               : 4 * (kbase + 63 - 1536) + 3;
        bool act[2];
        #pragma unroll
        for (int c = 0; c < 2; c++) act[c] = (efirst <= q0a[c] + 15);

        if (act[0] | act[1]) {
            // QK^T swapped, t-outer: K fragments (8 regs) feed both c-streams.
            f32x4 zt[2][4];
            __builtin_amdgcn_s_setprio(1);
            #pragma unroll
            for (int t = 0; t < 4; t++) {
                const int toff = (t & 1) * 4 + (t >> 1) * 32;
                const u16* kr = &Ksh[cur][(row0 + toff) * KSW];
                s16x8 fA = u2s8(*(const u16x8*)&kr[quad * 8]);
                s16x8 fB = u2s8(*(const u16x8*)&kr[32 + quad * 8]);
                #pragma unroll
                for (int c = 0; c < 2; c++) {
                    if (!act[c]) continue;
                    f32x4 z;
                    #pragma unroll
                    for (int rr = 0; rr < 4; rr++) z[rr] = 0.f;
                    z = mfma16(fA, qa[c][0], z);
                    zt[c][t] = mfma16(fB, qa[c][1], z);
                }
            }
            __builtin_amdgcn_s_setprio(0);

            s16x8 pfa[2], pfb[2];
            #pragma unroll
            for (int c = 0; c < 2; c++) {
                if (!act[c]) continue;
                if (elast > q0a[c]) {      // partial chunk: causal mask
                    int q = q0a[c] + l16;
                    int kmaxv = (lv == 0) ? q - kbase
                              : (lv == 1) ? ((q - 1) >> 1) - (kbase - 1024)
                                          : ((q - 3) >> 2) - (kbase - 1536);
                    int thrb = kmaxv - 8 * quad;
                    #pragma unroll
                    for (int t = 0; t < 4; t++) {
                        int thr = thrb - ((t & 1) * 4 + (t >> 1) * 32);
                        #pragma unroll
                        for (int rr = 0; rr < 4; rr++)
                            if (rr > thr) zt[c][t][rr] = -1e30f;
                    }
                }

                // softmax numerator: p = exp2(z) directly (pre-scaled, no max)
                float p[4][4]; float ps0 = 0.f, ps1 = 0.f;
                #pragma unroll
                for (int t = 0; t < 4; t++)
                    #pragma unroll
                    for (int rr = 0; rr < 4; rr++) {
                        p[t][rr] = exp2a(zt[c][t][rr]);
                        if (t & 1) ps1 += p[t][rr]; else ps0 += p[t][rr];
                    }
                float ps = ps0 + ps1;
                ps += __shfl_xor(ps, 16, 64);
                ps += __shfl_xor(ps, 32, 64);
                lrun[c] += ps;

                union { unsigned int w[4]; u16x8 v; } U0, U1;
                U0.w[0] = cvtpk(p[0][0], p[0][1]); U0.w[1] = cvtpk(p[0][2], p[0][3]);
                U0.w[2] = cvtpk(p[1][0], p[1][1]); U0.w[3] = cvtpk(p[1][2], p[1][3]);
                U1.w[0] = cvtpk(p[2][0], p[2][1]); U1.w[1] = cvtpk(p[2][2], p[2][3]);
                U1.w[2] = cvtpk(p[3][0], p[3][1]); U1.w[3] = cvtpk(p[3][2], p[3][3]);
                pfa[c] = u2s8(U0.v); pfb[c] = u2s8(U1.v);
            }

            // PV, j-outer: V fragments (8 regs) feed both c-streams.
            __builtin_amdgcn_s_setprio(1);
            #pragma unroll
            for (int j = 0; j < 4; j++) {
                const u16* vr = &Vsh[cur][(j * 16 + l16) * KSW];
                s16x8 vA = u2s8(*(const u16x8*)&vr[quad * 8]);
                s16x8 vB = u2s8(*(const u16x8*)&vr[32 + quad * 8]);
                #pragma unroll
                for (int c = 0; c < 2; c++) {
                    if (!act[c]) continue;
                    o[c][j] = mfma16(pfa[c], vA, o[c][j]);
                    o[c][j] = mfma16(pfb[c], vB, o[c][j]);
                }
            }
            __builtin_amdgcn_s_setprio(0);
        }

        if (ch + 1 < 28) {     // stage next chunk into the other buffer
            int nxt = cur ^ 1;
            *(u16x8*)&Ksh[nxt][kr0 * KSW + ku0] = kreg0;
            *(u16x8*)&Ksh[nxt][kr1 * KSW + ku1] = kreg1;
            *(u16x8*)&Vsh[nxt][kr0 * KSW + ku0] = vreg0;
            *(u16x8*)&Vsh[nxt][kr1 * KSW + ku1] = vreg1;
        }
        __syncthreads();
    }

    // epilogue per tile
    #pragma unroll
    for (int c = 0; c < 2; c++) {
        float il = 1.0f / lrun[c];
        float ilr[4];
        #pragma unroll
        for (int rr = 0; rr < 4; rr++) ilr[rr] = __shfl(il, quad * 4 + rr, 64);
        #pragma unroll
        for (int rr = 0; rr < 4; rr++) {
            int q = q0a[c] + quad * 4 + rr;
            #pragma unroll
            for (int j = 0; j < 4; j++)
                Hout[((size_t)(b * SS + q)) * DD + h * DH + j * 16 + l16] = f2b(o[c][j][rr] * ilr[rr]);
        }
    }
}

extern "C" void kernel_launch(void* const* d_in, const int* in_sizes, int n_in,
                              void* d_out, int out_size, void* d_ws, size_t ws_size,
                              hipStream_t stream)
{
    (void)in_sizes; (void)n_in; (void)out_size; (void)ws_size;
    const int* in_ex  = (const int*)d_in[0];
    const int* in_cat = (const int*)d_in[1];
    const int* in_res = (const int*)d_in[2];
    const float* in_pos = (const float*)d_in[3];
    const float* en_out = (const float*)d_in[4];
    const float* E_res  = (const float*)d_in[5];
    const float* E_ex   = (const float*)d_in[6];
    const float* E_cat  = (const float*)d_in[7];
    const float* g1 = (const float*)d_in[8],  *be1 = (const float*)d_in[9];
    const float* g2 = (const float*)d_in[10], *be2 = (const float*)d_in[11];
    const float* g3 = (const float*)d_in[12], *be3 = (const float*)d_in[13];
    const float* Wq1 = (const float*)d_in[14], *bq1 = (const float*)d_in[15];
    const float* Wk1 = (const float*)d_in[16], *bk1 = (const float*)d_in[17];
    const float* Wv1 = (const float*)d_in[18], *bv1 = (const float*)d_in[19];
    const float* Wo1 = (const float*)d_in[20], *bo1 = (const float*)d_in[21];
    const float* Wq2 = (const float*)d_in[22], *bq2 = (const float*)d_in[23];
    const float* Wk2 = (const float*)d_in[24], *bk2 = (const float*)d_in[25];
    const float* Wv2 = (const float*)d_in[26], *bv2 = (const float*)d_in[27];
    const float* Wo2 = (const float*)d_in[28], *bo2 = (const float*)d_in[29];
    const float* fW1 = (const float*)d_in[30], *fb1 = (const float*)d_in[31];
    const float* fW2 = (const float*)d_in[32], *fb2 = (const float*)d_in[33];

    char* ws = (char*)d_ws;
    const size_t U = (size_t)NROW * DD * 2;        // 16.78 MB
    float* x1 = (float*)(ws);                      // 2U f32  [ph4: en bf16 in 1st U; then x3 f32]
    u16* qb   = (u16*)(ws + 2 * U);                // 1U
    u16* vb   = (u16*)(ws + 3 * U);                // 1U
    u16* hb   = (u16*)(ws + 4 * U);                // 1U  [ph5: ff1]
    u16* kp   = (u16*)(ws + 5 * U);                // 1.75U (B,H,1792,64)
    u16* vpt  = (u16*)(ws + 5 * U + 7 * U / 4);    // 1.75U (B,H,64,1792)
    u16* wt   = (u16*)(ws + 8 * U + U / 2);        // 10 x 512KB bf16 transposed weights
    float* x2 = (float*)d_out;                     // d_out doubles as x2 (fully overwritten at end)
    u16* en = (u16*)(ws);                          // phase-4 alias of dead x1 slot
    float* x3 = x1;                                // phase-4 output slot
    float* x4 = (float*)(ws + 5 * U);              // phase-5 alias over kp/vpt (dead)
    u16* ff1 = hb;                                 // phase-5 alias

    W10 wp;
    const float* wsrc[10] = {Wq1, Wk1, Wv1, Wo1, Wq2, Wk2, Wv2, Wo2, fW1, fW2};
    for (int i = 0; i < 10; i++) wp.p[i] = wsrc[i];
    transpose_all_k<<<dim3(8, 8, 10), 256, 0, stream>>>(wp, wt);
    u16* tWq1 = wt,            *tWk1 = wt + 262144,   *tWv1 = wt + 2*262144, *tWo1 = wt + 3*262144;
    u16* tWq2 = wt + 4*262144, *tWk2 = wt + 5*262144, *tWv2 = wt + 6*262144, *tWo2 = wt + 7*262144;
    u16* tF1  = wt + 8*262144, *tF2  = wt + 9*262144;

    dim3 ggrid(4, 128);
    dim3 vtgrid(16, 8, 16);
    const float QSC = 0.18033688f;   // 0.125 * log2(e): folded into Q projection

    // phase 2: x1 = LN1(embed sum)   (f32)
    embed_ln_k<<<4096, 256, 0, stream>>>(in_ex, in_cat, in_res, in_pos,
                                         E_res, E_ex, E_cat, g1, be1, x1);

    // phase 3: self-attention; x2 = x1 + attn(x1) @ Wo1
    gemm_k<true,false,false,true,false><<<ggrid, 256, 0, stream>>>(x1, tWq1, bq1, nullptr, qb, NROW, 512, QSC);
    gemm_k<true,false,false,true,true ><<<ggrid, 256, 0, stream>>>(x1, tWk1, bk1, nullptr, kp, NROW, 512, 1.0f);
    gemm_k<true,false,false,true,false><<<ggrid, 256, 0, stream>>>(x1, tWv1, bv1, nullptr, vb, NROW, 512, 1.0f);
    pool_vt_k<<<vtgrid, 256, 0, stream>>>(vb, vpt);
    attn_k<<<1024, 256, 0, stream>>>(qb, kp, vpt, hb);
    gemm_k<false,false,true,false,false><<<ggrid, 256, 0, stream>>>(hb, tWo1, bo1, x1, x2, NROW, 512, 1.0f);

    // phase 4: cross-attention; x3 = x2 + attn(q=x2, kv=en) @ Wo2
    ln_k<true><<<4096, 256, 0, stream>>>(en_out, g2, be2, en);
    gemm_k<true,false,false,true,false><<<ggrid, 256, 0, stream>>>(x2, tWq2, bq2, nullptr, qb, NROW, 512, QSC);
    gemm_k<false,false,false,true,true ><<<ggrid, 256, 0, stream>>>(en, tWk2, bk2, nullptr, kp, NROW, 512, 1.0f);
    gemm_k<false,false,false,true,false><<<ggrid, 256, 0, stream>>>(en, tWv2, bv2, nullptr, vb, NROW, 512, 1.0f);
    pool_vt_k<<<vtgrid, 256, 0, stream>>>(vb, vpt);
    attn_k<<<1024, 256, 0, stream>>>(qb, kp, vpt, hb);
    gemm_k<false,false,true,false,false><<<ggrid, 256, 0, stream>>>(hb, tWo2, bo2, x2, x3, NROW, 512, 1.0f);

    // phase 5: x4 = LN3(x3); out = x4 + relu(x4@fW1+fb1)@fW2+fb2
    ln_k<false><<<4096, 256, 0, stream>>>(x3, g3, be3, x4);
    gemm_k<true,true,false,true,false><<<ggrid, 256, 0, stream>>>(x4, tF1, fb1, nullptr, ff1, NROW, 512, 1.0f);
    gemm_k<false,false,true,false,false><<<ggrid, 256, 0, stream>>>(ff1, tF2, fb2, x4, (float*)d_out, NROW, 512, 1.0f);
}

// Round 8
// 601.205 us; speedup vs baseline: 1.1805x; 1.0620x over previous
//
#include <hip/hip_runtime.h>

// Decoder block, MI355X gfx950. ALL float tensors f32 (per reference); ints
// int32; output f32. GEMMs + attention use bf16 MFMA internally, f32
// accumulate; residual stream kept in f32.

#define BB 16
#define SS 1024
#define DD 512
#define HH 8
#define DH 64
#define KTOT 1792          // 1024 + 512 + 256 pyramid keys
#define NROW (BB*SS)       // 16384
#define KSW 80             // attn LDS row stride (u16): 40 dwords == 8 mod 32 -> conflict-free

typedef unsigned short u16;
typedef __attribute__((ext_vector_type(8))) u16 u16x8;
typedef __attribute__((ext_vector_type(4))) u16 u16x4;
typedef __attribute__((ext_vector_type(8))) short s16x8;
typedef __attribute__((ext_vector_type(4))) float f32x4;

__device__ __forceinline__ float b2f(u16 u) {
    return __uint_as_float(((unsigned int)u) << 16);
}
__device__ __forceinline__ u16 f2b(float f) {
    unsigned int u = __float_as_uint(f);
    return (u16)((u + 0x7FFF + ((u >> 16) & 1)) >> 16);
}
__device__ __forceinline__ s16x8 u2s8(u16x8 u) {
    union { u16x8 u; s16x8 s; } x; x.u = u; return x.s;
}
__device__ __forceinline__ f32x4 mfma16(s16x8 a, s16x8 b, f32x4 c) {
    return __builtin_amdgcn_mfma_f32_16x16x32_bf16(a, b, c, 0, 0, 0);
}
__device__ __forceinline__ float wave_sum(float v) {
    #pragma unroll
    for (int m = 1; m < 64; m <<= 1) v += __shfl_xor(v, m, 64);
    return v;
}
// native 2^x
__device__ __forceinline__ float exp2a(float x) {
    float r;
    asm("v_exp_f32 %0, %1" : "=v"(r) : "v"(x));
    return r;
}
// packed bf16 convert (RNE): low16 = bf16(a), high16 = bf16(b)
__device__ __forceinline__ unsigned int cvtpk(float a, float b) {
    unsigned int r;
    asm("v_cvt_pk_bf16_f32 %0, %1, %2" : "=v"(r) : "v"(a), "v"(b));
    return r;
}
// async global->LDS 16B: per-lane global addr, LDS dest = wave-uniform base + lane*16
__device__ __forceinline__ void gl16(const void* g, void* l) {
    __builtin_amdgcn_global_load_lds(
        (const __attribute__((address_space(1))) void*)(unsigned long long)g,
        (__attribute__((address_space(3))) void*)(unsigned int)(unsigned long long)l,
        16, 0, 0);
}

// ---------------- embed + LN1 : one wave per (b,s) row, f32 in/out ----------------
__global__ __launch_bounds__(256) void embed_ln_k(
    const int* __restrict__ in_ex, const int* __restrict__ in_cat,
    const int* __restrict__ in_res, const float* __restrict__ in_pos,
    const float* __restrict__ E_res, const float* __restrict__ E_ex,
    const float* __restrict__ E_cat, const float* __restrict__ g,
    const float* __restrict__ be, float* __restrict__ out)
{
    int wave = threadIdx.x >> 6, lane = threadIdx.x & 63;
    int row = blockIdx.x * 4 + wave;          // < 16384
    int res = in_res[row];
    int ex  = in_ex[row] + 10000 * res;
    int cat = in_cat[row] + 300 * res;
    int d0 = lane * 8;
    const float* pr = &E_res[(size_t)res * DD + d0];
    const float* pe = &E_ex[(size_t)ex * DD + d0];
    const float* pc = &E_cat[(size_t)cat * DD + d0];
    const float* pp = &in_pos[(size_t)row * DD + d0];
    float x[8]; float s = 0.f;
    #pragma unroll
    for (int j = 0; j < 8; j++) { x[j] = pr[j] + pe[j] + pc[j] + pp[j]; s += x[j]; }
    s = wave_sum(s);
    float mean = s * (1.0f / DD);
    float vs = 0.f;
    #pragma unroll
    for (int j = 0; j < 8; j++) { float d = x[j] - mean; vs += d * d; }
    vs = wave_sum(vs);
    float rstd = rsqrtf(vs * (1.0f / DD) + 1e-5f);
    #pragma unroll
    for (int j = 0; j < 8; j++)
        out[(size_t)row * DD + d0 + j] = (x[j] - mean) * rstd * g[d0 + j] + be[d0 + j];
}

// ---------------- generic row LayerNorm: f32 in, f32 or bf16 out ----------------
template<bool OUTB>
__global__ __launch_bounds__(256) void ln_k(
    const float* __restrict__ x, const float* __restrict__ g,
    const float* __restrict__ be, void* __restrict__ outv)
{
    int wave = threadIdx.x >> 6, lane = threadIdx.x & 63;
    int row = blockIdx.x * 4 + wave;
    int d0 = lane * 8;
    const float* px = &x[(size_t)row * DD + d0];
    float xv[8]; float s = 0.f;
    #pragma unroll
    for (int j = 0; j < 8; j++) { xv[j] = px[j]; s += xv[j]; }
    s = wave_sum(s);
    float mean = s * (1.0f / DD);
    float vs = 0.f;
    #pragma unroll
    for (int j = 0; j < 8; j++) { float d = xv[j] - mean; vs += d * d; }
    vs = wave_sum(vs);
    float rstd = rsqrtf(vs * (1.0f / DD) + 1e-5f);
    #pragma unroll
    for (int j = 0; j < 8; j++) {
        float v = (xv[j] - mean) * rstd * g[d0 + j] + be[d0 + j];
        if (OUTB) ((u16*)outv)[(size_t)row * DD + d0 + j] = f2b(v);
        else      ((float*)outv)[(size_t)row * DD + d0 + j] = v;
    }
}

// ---------------- all-weight transpose + cast via LDS tiles ----------------
// f32 W[k][n] (512x512) -> bf16 Wt[n][k], 10 weights in one launch.
struct W10 { const float* p[10]; };
__global__ __launch_bounds__(256) void transpose_all_k(W10 wp, u16* __restrict__ dst)
{
    __shared__ __align__(16) u16 T[64 * 72];
    int w = blockIdx.z;
    const float* src = wp.p[w];
    u16* d = dst + (size_t)w * 262144;
    int tk = blockIdx.x;          // k-tile 0..7
    int tn = blockIdx.y;          // n-tile 0..7
    int tid = threadIdx.x;
    {
        int r = tid >> 4;         // 0..15
        int c4 = (tid & 15) * 4;  // 0..60
        #pragma unroll
        for (int it = 0; it < 4; it++) {
            int kr = it * 16 + r;
            const float* s4 = &src[(size_t)(tk * 64 + kr) * 512 + tn * 64 + c4];
            f32x4 v = *(const f32x4*)s4;
            *(unsigned int*)&T[kr * 72 + c4]     = cvtpk(v[0], v[1]);
            *(unsigned int*)&T[kr * 72 + c4 + 2] = cvtpk(v[2], v[3]);
        }
    }
    __syncthreads();
    {
        int nn = tid >> 2;            // 0..63
        int k16 = (tid & 3) * 16;     // 0,16,32,48
        u16x8 a, b;
        #pragma unroll
        for (int j = 0; j < 8; j++) {
            a[j] = T[(k16 + j) * 72 + nn];
            b[j] = T[(k16 + 8 + j) * 72 + nn];
        }
        u16* o = &d[(size_t)(tn * 64 + nn) * 512 + tk * 64 + k16];
        *(u16x8*)&o[0] = a;
        *(u16x8*)&o[8] = b;
    }
}

// ---------------- V pyramid pool via LDS transpose ----------------
__global__ __launch_bounds__(256) void pool_vt_k(const u16* __restrict__ Vp, u16* __restrict__ VPt)
{
    __shared__ __align__(16) u16 T[64 * 72];   // local s x d, stride 72 (16B-aligned rows)
    int tid = threadIdx.x;
    int st = blockIdx.x;                        // 0..15 s-tile
    int h  = blockIdx.y;                        // 0..7
    int b  = blockIdx.z;                        // 0..15
    int s0 = st * 64;
    {
        const u16* src = &Vp[((size_t)(b * SS + s0)) * DD + h * DH];
        #pragma unroll
        for (int it = 0; it < 2; it++) {
            int idx = it * 256 + tid;           // 512 x 16B units
            int row = idx >> 3, unit = idx & 7;
            *(u16x8*)&T[row * 72 + unit * 8] =
                *(const u16x8*)&src[(size_t)row * DD + unit * 8];
        }
    }
    __syncthreads();
    int d = tid & 63, g = tid >> 6;             // 4 waves: g = 0..3
    size_t obase = ((size_t)(b * HH + h) * DH + d) * KTOT;
    // level 0: 64 keys at s0
    #pragma unroll
    for (int gg = 0; gg < 2; gg++) {
        int grp = g * 2 + gg;                   // s chunk of 8
        u16x8 v;
        #pragma unroll
        for (int j = 0; j < 8; j++) v[j] = T[(grp * 8 + j) * 72 + d];
        *(u16x8*)&VPt[obase + s0 + grp * 8] = v;
    }
    // level 1: 32 keys at 1024 + st*32
    {
        u16x8 v;
        #pragma unroll
        for (int j = 0; j < 8; j++) {
            int sl = g * 8 + j;                 // 0..31
            float a = b2f(T[(2 * sl) * 72 + d]) + b2f(T[(2 * sl + 1) * 72 + d]);
            v[j] = f2b(a * 0.5f);
        }
        *(u16x8*)&VPt[obase + 1024 + st * 32 + g * 8] = v;
    }
    // level 2: 16 keys at 1536 + st*16
    {
        u16x4 v;
        #pragma unroll
        for (int j = 0; j < 4; j++) {
            int s2 = g * 4 + j;                 // 0..15
            float a = 0.f;
            #pragma unroll
            for (int i = 0; i < 4; i++) a += b2f(T[(4 * s2 + i) * 72 + d]);
            v[j] = f2b(a * 0.25f);
        }
        *(u16x4*)&VPt[obase + 1536 + st * 16 + g * 4] = v;
    }
}

// ---------------- MFMA GEMM, double-buffered: C(M,512) = A @ W + bias [relu][+resid] ----------------
template<bool AF32, bool RELU, bool RES, bool OUTB, bool KLAY>
__global__ __launch_bounds__(256) void gemm_k(
    const void* __restrict__ Av, const u16* __restrict__ Wt,
    const float* __restrict__ bias, const float* __restrict__ resid,
    void* __restrict__ Cv, int M, int K, float oscale)
{
    const int N = 512;
    constexpr int ASW = AF32 ? 40 : 32;
    __shared__ __align__(16) u16 As[2][128 * ASW];
    __shared__ __align__(16) u16 Bs[2][128 * 32];
    int tid = threadIdx.x;
    int wave = tid >> 6, lane = tid & 63;
    int quad = lane >> 4, l16 = lane & 15;
    int m0 = blockIdx.y * 128, n0 = blockIdx.x * 128;
    int wm = (wave >> 1) * 64, wn = (wave & 1) * 64;
    int r = tid >> 1, cg = (tid & 1) * 16;          // AF32 manual staging
    int grow = wave * 16 + (lane >> 2);             // gl16 row (64-row half)
    int gk = (lane & 3) * 8;                        // u16 offset (16B unit)
    const float* Af = (const float*)Av;
    const u16*  Ab = (const u16*)Av;
    f32x4 acc[4][4];
    #pragma unroll
    for (int i = 0; i < 4; i++)
        #pragma unroll
        for (int j = 0; j < 4; j++)
            #pragma unroll
            for (int rr = 0; rr < 4; rr++) acc[i][j][rr] = 0.f;

    const int NT = K >> 5;
    f32x4 s0, s1, s2, s3;                           // AF32 in-flight A regs

    #define ISSUE_B(t, buf) { int k0_ = (t) << 5; \
        gl16(&Wt[(size_t)(n0 + grow) * 512 + k0_ + gk],      &Bs[buf][grow * 32 + gk]); \
        gl16(&Wt[(size_t)(n0 + 64 + grow) * 512 + k0_ + gk], &Bs[buf][(64 + grow) * 32 + gk]); }
    #define ISSUE_A16(t, buf) { int k0_ = (t) << 5; \
        gl16(&Ab[(size_t)(m0 + grow) * K + k0_ + gk],      &As[buf][grow * 32 + gk]); \
        gl16(&Ab[(size_t)(m0 + 64 + grow) * K + k0_ + gk], &As[buf][(64 + grow) * 32 + gk]); }
    #define LOAD_A32(t) { const float* src_ = &Af[(size_t)(m0 + r) * K + ((t) << 5) + cg]; \
        s0 = *(const f32x4*)&src_[0];  s1 = *(const f32x4*)&src_[4]; \
        s2 = *(const f32x4*)&src_[8];  s3 = *(const f32x4*)&src_[12]; }
    #define WRITE_A32(buf) { union { unsigned int w[4]; u16x8 v; } L_, H_; \
        L_.w[0] = cvtpk(s0[0], s0[1]); L_.w[1] = cvtpk(s0[2], s0[3]); \
        L_.w[2] = cvtpk(s1[0], s1[1]); L_.w[3] = cvtpk(s1[2], s1[3]); \
        H_.w[0] = cvtpk(s2[0], s2[1]); H_.w[1] = cvtpk(s2[2], s2[3]); \
        H_.w[2] = cvtpk(s3[0], s3[1]); H_.w[3] = cvtpk(s3[2], s3[3]); \
        *(u16x8*)&As[buf][r * ASW + cg]     = L_.v; \
        *(u16x8*)&As[buf][r * ASW + cg + 8] = H_.v; }

    if (AF32) { LOAD_A32(0); WRITE_A32(0); }
    else      { ISSUE_A16(0, 0); }
    ISSUE_B(0, 0);
    __syncthreads();

    for (int t = 0; t < NT; ++t) {
        int cur = t & 1, nxt = cur ^ 1;
        if (t + 1 < NT) {
            if (AF32) { LOAD_A32(t + 1); }
            else      { ISSUE_A16(t + 1, nxt); }
            ISSUE_B(t + 1, nxt);
        }
        s16x8 af[4], bfr[4];
        #pragma unroll
        for (int i = 0; i < 4; i++)
            af[i] = u2s8(*(const u16x8*)&As[cur][(wm + i * 16 + l16) * ASW + quad * 8]);
        #pragma unroll
        for (int j = 0; j < 4; j++)
            bfr[j] = u2s8(*(const u16x8*)&Bs[cur][(wn + j * 16 + l16) * 32 + quad * 8]);
        #pragma unroll
        for (int i = 0; i < 4; i++)
            #pragma unroll
            for (int j = 0; j < 4; j++)
                acc[i][j] = mfma16(af[i], bfr[j], acc[i][j]);
        if (AF32 && t + 1 < NT) { WRITE_A32(nxt); }
        __syncthreads();
    }

    #pragma unroll
    for (int j = 0; j < 4; j++) {
        int col = n0 + wn + j * 16 + l16;
        float bv = bias[col];
        #pragma unroll
        for (int i = 0; i < 4; i++) {
            int rowb = m0 + wm + i * 16 + quad * 4;
            if (KLAY) {
                float vv[4];
                #pragma unroll
                for (int rr = 0; rr < 4; rr++) vv[rr] = acc[i][j][rr] + bv;
                int b_ = rowb >> 10, s_ = rowb & 1023;      // s_ multiple of 4
                size_t bh = (size_t)(b_ * HH + (col >> 6)) * KTOT;
                int dd = col & 63;
                u16* C16 = (u16*)Cv;
                #pragma unroll
                for (int rr = 0; rr < 4; rr++)
                    C16[(bh + s_ + rr) * DH + dd] = f2b(vv[rr]);
                C16[(bh + 1024 + (s_ >> 1)) * DH + dd]     = f2b((vv[0] + vv[1]) * 0.5f);
                C16[(bh + 1024 + (s_ >> 1) + 1) * DH + dd] = f2b((vv[2] + vv[3]) * 0.5f);
                C16[(bh + 1536 + (s_ >> 2)) * DH + dd]     = f2b((vv[0] + vv[1] + vv[2] + vv[3]) * 0.25f);
            } else {
                #pragma unroll
                for (int rr = 0; rr < 4; rr++) {
                    float v = (acc[i][j][rr] + bv) * oscale;
                    if (RELU) v = fmaxf(v, 0.f);
                    int row = rowb + rr;
                    if (RES) v += resid[(size_t)row * N + col];
                    if (OUTB) ((u16*)Cv)[(size_t)row * N + col] = f2b(v);
                    else      ((float*)Cv)[(size_t)row * N + col] = v;
                }
            }
        }
    }
    #undef ISSUE_B
    #undef ISSUE_A16
    #undef LOAD_A32
    #undef WRITE_A32
}

// ---------------- fused multi-output GEMM: up to 3 weight/output sets, one A ----------------
// grid (4*NG, 128); gsel = blockIdx.x>>2 selects {W,bias,C,mode,oscale}.
// mode 0 = bf16 out with oscale; mode 1 = KLAY (KP layout + level-1/2 pools).
struct FArgs {
    const u16* W[3]; const float* bias[3]; void* C[3];
    float osc[3]; int mode[3];
};
template<bool AF32>
__global__ __launch_bounds__(256) void fused_gemm_k(
    const void* __restrict__ Av, FArgs fa, int M, int K)
{
    constexpr int ASW = AF32 ? 40 : 32;
    __shared__ __align__(16) u16 As[2][128 * ASW];
    __shared__ __align__(16) u16 Bs[2][128 * 32];
    int gsel = blockIdx.x >> 2;
    int n0 = (blockIdx.x & 3) * 128;
    const u16* Wt = fa.W[gsel];
    const float* bias = fa.bias[gsel];
    void* Cv = fa.C[gsel];
    float oscale = fa.osc[gsel];
    int mode = fa.mode[gsel];

    int tid = threadIdx.x;
    int wave = tid >> 6, lane = tid & 63;
    int quad = lane >> 4, l16 = lane & 15;
    int m0 = blockIdx.y * 128;
    int wm = (wave >> 1) * 64, wn = (wave & 1) * 64;
    int r = tid >> 1, cg = (tid & 1) * 16;
    int grow = wave * 16 + (lane >> 2);
    int gk = (lane & 3) * 8;
    const float* Af = (const float*)Av;
    const u16*  Ab = (const u16*)Av;
    f32x4 acc[4][4];
    #pragma unroll
    for (int i = 0; i < 4; i++)
        #pragma unroll
        for (int j = 0; j < 4; j++)
            #pragma unroll
            for (int rr = 0; rr < 4; rr++) acc[i][j][rr] = 0.f;

    const int NT = K >> 5;
    f32x4 s0, s1, s2, s3;

    #define ISSUE_B(t, buf) { int k0_ = (t) << 5; \
        gl16(&Wt[(size_t)(n0 + grow) * 512 + k0_ + gk],      &Bs[buf][grow * 32 + gk]); \
        gl16(&Wt[(size_t)(n0 + 64 + grow) * 512 + k0_ + gk], &Bs[buf][(64 + grow) * 32 + gk]); }
    #define ISSUE_A16(t, buf) { int k0_ = (t) << 5; \
        gl16(&Ab[(size_t)(m0 + grow) * K + k0_ + gk],      &As[buf][grow * 32 + gk]); \
        gl16(&Ab[(size_t)(m0 + 64 + grow) * K + k0_ + gk], &As[buf][(64 + grow) * 32 + gk]); }
    #define LOAD_A32(t) { const float* src_ = &Af[(size_t)(m0 + r) * K + ((t) << 5) + cg]; \
        s0 = *(const f32x4*)&src_[0];  s1 = *(const f32x4*)&src_[4]; \
        s2 = *(const f32x4*)&src_[8];  s3 = *(const f32x4*)&src_[12]; }
    #define WRITE_A32(buf) { union { unsigned int w[4]; u16x8 v; } L_, H_; \
        L_.w[0] = cvtpk(s0[0], s0[1]); L_.w[1] = cvtpk(s0[2], s0[3]); \
        L_.w[2] = cvtpk(s1[0], s1[1]); L_.w[3] = cvtpk(s1[2], s1[3]); \
        H_.w[0] = cvtpk(s2[0], s2[1]); H_.w[1] = cvtpk(s2[2], s2[3]); \
        H_.w[2] = cvtpk(s3[0], s3[1]); H_.w[3] = cvtpk(s3[2], s3[3]); \
        *(u16x8*)&As[buf][r * ASW + cg]     = L_.v; \
        *(u16x8*)&As[buf][r * ASW + cg + 8] = H_.v; }

    if (AF32) { LOAD_A32(0); WRITE_A32(0); }
    else      { ISSUE_A16(0, 0); }
    ISSUE_B(0, 0);
    __syncthreads();

    for (int t = 0; t < NT; ++t) {
        int cur = t & 1, nxt = cur ^ 1;
        if (t + 1 < NT) {
            if (AF32) { LOAD_A32(t + 1); }
            else      { ISSUE_A16(t + 1, nxt); }
            ISSUE_B(t + 1, nxt);
        }
        s16x8 af[4], bfr[4];
        #pragma unroll
        for (int i = 0; i < 4; i++)
            af[i] = u2s8(*(const u16x8*)&As[cur][(wm + i * 16 + l16) * ASW + quad * 8]);
        #pragma unroll
        for (int j = 0; j < 4; j++)
            bfr[j] = u2s8(*(const u16x8*)&Bs[cur][(wn + j * 16 + l16) * 32 + quad * 8]);
        #pragma unroll
        for (int i = 0; i < 4; i++)
            #pragma unroll
            for (int j = 0; j < 4; j++)
                acc[i][j] = mfma16(af[i], bfr[j], acc[i][j]);
        if (AF32 && t + 1 < NT) { WRITE_A32(nxt); }
        __syncthreads();
    }
    #undef ISSUE_B
    #undef ISSUE_A16
    #undef LOAD_A32
    #undef WRITE_A32

    if (mode == 1) {          // KLAY epilogue (K projection + pyramid pools)
        #pragma unroll
        for (int j = 0; j < 4; j++) {
            int col = n0 + wn + j * 16 + l16;
            float bv = bias[col];
            #pragma unroll
            for (int i = 0; i < 4; i++) {
                int rowb = m0 + wm + i * 16 + quad * 4;
                float vv[4];
                #pragma unroll
                for (int rr = 0; rr < 4; rr++) vv[rr] = acc[i][j][rr] + bv;
                int b_ = rowb >> 10, s_ = rowb & 1023;
                size_t bh = (size_t)(b_ * HH + (col >> 6)) * KTOT;
                int dd = col & 63;
                u16* C16 = (u16*)Cv;
                #pragma unroll
                for (int rr = 0; rr < 4; rr++)
                    C16[(bh + s_ + rr) * DH + dd] = f2b(vv[rr]);
                C16[(bh + 1024 + (s_ >> 1)) * DH + dd]     = f2b((vv[0] + vv[1]) * 0.5f);
                C16[(bh + 1024 + (s_ >> 1) + 1) * DH + dd] = f2b((vv[2] + vv[3]) * 0.5f);
                C16[(bh + 1536 + (s_ >> 2)) * DH + dd]     = f2b((vv[0] + vv[1] + vv[2] + vv[3]) * 0.25f);
            }
        }
    } else {                  // bf16 out with oscale
        #pragma unroll
        for (int j = 0; j < 4; j++) {
            int col = n0 + wn + j * 16 + l16;
            float bv = bias[col];
            #pragma unroll
            for (int i = 0; i < 4; i++) {
                int rowb = m0 + wm + i * 16 + quad * 4;
                #pragma unroll
                for (int rr = 0; rr < 4; rr++) {
                    float v = (acc[i][j][rr] + bv) * oscale;
                    ((u16*)Cv)[(size_t)(rowb + rr) * 512 + col] = f2b(v);
                }
            }
        }
    }
}

// ---------------- MFMA flash pyramid attention: 8-way q-split, 1 tile/wave ----------------
// 1024 blocks x 512 threads (8 waves) -> 32 waves/CU (grid exactly fills the
// chip). Block owns (b,h) with an 8-way split x; wave w handles the single
// tile w*8 + x (intra-block tiles span 0..63 so per-chunk block time ~= the
// busiest wave, same as the paired layout; inter-block imbalance <= ~9%).
// id&7 = h keeps all 8 blocks sharing one (b,h)'s KV on the same XCD (L2).
// Round-4 proven structure: single-buffered K/V LDS, 2 barriers/chunk,
// register prefetch one chunk ahead. Swapped QK (mfma(K,Q)) + sigma key
// permutation put scores directly in PV A-fragment order; Q pre-scaled by
// 0.125*log2e so p = exp2(z) with no online max (|z| << 1 by construction).
__global__ __launch_bounds__(512) void attn_k(
    const u16* __restrict__ Qp, const u16* __restrict__ KP,
    const u16* __restrict__ VPt, u16* __restrict__ Hout)
{
    __shared__ __align__(16) u16 Ksh[64 * KSW];   // keys x dh
    __shared__ __align__(16) u16 Vsh[64 * KSW];   // dh x keys
    int tid = threadIdx.x;
    int wave = tid >> 6, lane = tid & 63;
    int quad = lane >> 4, l16 = lane & 15;
    int id = blockIdx.x;
    int h = id & 7;
    int inner = id >> 3;
    int x = inner & 7, b = inner >> 3;

    int tile = wave * 8 + x;               // 0..63
    int q0 = tile * 16;

    const u16* Kb = KP  + ((size_t)(b * HH + h)) * KTOT * DH;
    const u16* Vt = VPt + ((size_t)(b * HH + h)) * DH * KTOT;

    s16x8 qa0, qa1;
    f32x4 o[4];
    float lrun = 0.f;
    {
        const u16* qrow = Qp + ((size_t)(b * SS + q0 + l16)) * DD + h * DH;
        qa0 = u2s8(*(const u16x8*)&qrow[quad * 8]);
        qa1 = u2s8(*(const u16x8*)&qrow[32 + quad * 8]);
        #pragma unroll
        for (int j = 0; j < 4; j++)
            #pragma unroll
            for (int rr = 0; rr < 4; rr++) o[j][rr] = 0.f;
    }

    // sigma row base for this lane (K-fragment row within chunk; t adds {0,4,32,36})
    int row0 = 8 * (l16 >> 2) + (l16 & 3);

    int srow = tid >> 3, sunit = tid & 7;  // staging: 64 rows x 8 units of 16B
    // prefetch chunk 0
    u16x8 kreg = *(const u16x8*)&Kb[(size_t)tid * 8];
    u16x8 vreg = *(const u16x8*)&Vt[(size_t)srow * KTOT + sunit * 8];

    for (int ch = 0; ch < 28; ch++) {
        int kbase = ch * 64;
        int lv = (ch < 16) ? 0 : (ch < 24) ? 1 : 2;
        __syncthreads();   // prior chunk's LDS reads done
        *(u16x8*)&Ksh[srow * KSW + sunit * 8] = kreg;
        *(u16x8*)&Vsh[srow * KSW + sunit * 8] = vreg;
        __syncthreads();   // staging visible
        if (ch + 1 < 28) { // prefetch next chunk (overlaps compute below)
            int nb = (ch + 1) * 64;
            kreg = *(const u16x8*)&Kb[(size_t)nb * DH + tid * 8];
            vreg = *(const u16x8*)&Vt[(size_t)srow * KTOT + nb + sunit * 8];
        }

        int efirst = (lv == 0) ? kbase
                   : (lv == 1) ? 2 * (kbase - 1024) + 1
                               : 4 * (kbase - 1536) + 3;
        if (efirst > q0 + 15) continue;    // wave-uniform

        int elast = (lv == 0) ? kbase + 63
                  : (lv == 1) ? 2 * (kbase + 63 - 1024) + 1
                              : 4 * (kbase + 63 - 1536) + 3;

        // QK^T swapped: D[key][q]; kk(t,quad,rr) = toff(t) + 8*quad + rr
        f32x4 zt[4];
        __builtin_amdgcn_s_setprio(1);
        #pragma unroll
        for (int t = 0; t < 4; t++) {
            const int toff = (t & 1) * 4 + (t >> 1) * 32;
            const u16* kr = &Ksh[(row0 + toff) * KSW];
            s16x8 kf0 = u2s8(*(const u16x8*)&kr[quad * 8]);
            s16x8 kf1 = u2s8(*(const u16x8*)&kr[32 + quad * 8]);
            f32x4 z;
            #pragma unroll
            for (int rr = 0; rr < 4; rr++) z[rr] = 0.f;
            z = mfma16(kf0, qa0, z);
            zt[t] = mfma16(kf1, qa1, z);
        }
        __builtin_amdgcn_s_setprio(0);

        if (elast > q0) {              // partial chunk: apply causal mask
            int q = q0 + l16;
            int kmaxv = (lv == 0) ? q - kbase
                      : (lv == 1) ? ((q - 1) >> 1) - (kbase - 1024)
                                  : ((q - 3) >> 2) - (kbase - 1536);
            int thrb = kmaxv - 8 * quad;
            #pragma unroll
            for (int t = 0; t < 4; t++) {
                int thr = thrb - ((t & 1) * 4 + (t >> 1) * 32);
                #pragma unroll
                for (int rr = 0; rr < 4; rr++)
                    if (rr > thr) zt[t][rr] = -1e30f;
            }
        }

        // softmax numerator: p = exp2(z) directly (pre-scaled, no max)
        float p[4][4]; float ps0 = 0.f, ps1 = 0.f;
        #pragma unroll
        for (int t = 0; t < 4; t++)
            #pragma unroll
            for (int rr = 0; rr < 4; rr++) {
                p[t][rr] = exp2a(zt[t][rr]);
                if (t & 1) ps1 += p[t][rr]; else ps0 += p[t][rr];
            }
        float ps = ps0 + ps1;
        ps += __shfl_xor(ps, 16, 64);
        ps += __shfl_xor(ps, 32, 64);
        lrun += ps;

        // pack P into PV A-fragments: slots already in order thanks to sigma
        union { unsigned int w[4]; u16x8 v; } U0, U1;
        U0.w[0] = cvtpk(p[0][0], p[0][1]); U0.w[1] = cvtpk(p[0][2], p[0][3]);
        U0.w[2] = cvtpk(p[1][0], p[1][1]); U0.w[3] = cvtpk(p[1][2], p[1][3]);
        U1.w[0] = cvtpk(p[2][0], p[2][1]); U1.w[1] = cvtpk(p[2][2], p[2][3]);
        U1.w[2] = cvtpk(p[3][0], p[3][1]); U1.w[3] = cvtpk(p[3][2], p[3][3]);
        s16x8 pf0 = u2s8(U0.v), pf1 = u2s8(U1.v);

        // PV from LDS V (dh-major rows)
        __builtin_amdgcn_s_setprio(1);
        #pragma unroll
        for (int j = 0; j < 4; j++) {
            const u16* vr = &Vsh[(j * 16 + l16) * KSW];
            o[j] = mfma16(pf0, u2s8(*(const u16x8*)&vr[quad * 8]), o[j]);
            o[j] = mfma16(pf1, u2s8(*(const u16x8*)&vr[32 + quad * 8]), o[j]);
        }
        __builtin_amdgcn_s_setprio(0);
    }

    // epilogue
    {
        float il = 1.0f / lrun;
        float ilr[4];
        #pragma unroll
        for (int rr = 0; rr < 4; rr++) ilr[rr] = __shfl(il, quad * 4 + rr, 64);
        #pragma unroll
        for (int rr = 0; rr < 4; rr++) {
            int q = q0 + quad * 4 + rr;
            #pragma unroll
            for (int j = 0; j < 4; j++)
                Hout[((size_t)(b * SS + q)) * DD + h * DH + j * 16 + l16] = f2b(o[j][rr] * ilr[rr]);
        }
    }
}

extern "C" void kernel_launch(void* const* d_in, const int* in_sizes, int n_in,
                              void* d_out, int out_size, void* d_ws, size_t ws_size,
                              hipStream_t stream)
{
    (void)in_sizes; (void)n_in; (void)out_size; (void)ws_size;
    const int* in_ex  = (const int*)d_in[0];
    const int* in_cat = (const int*)d_in[1];
    const int* in_res = (const int*)d_in[2];
    const float* in_pos = (const float*)d_in[3];
    const float* en_out = (const float*)d_in[4];
    const float* E_res  = (const float*)d_in[5];
    const float* E_ex   = (const float*)d_in[6];
    const float* E_cat  = (const float*)d_in[7];
    const float* g1 = (const float*)d_in[8],  *be1 = (const float*)d_in[9];
    const float* g2 = (const float*)d_in[10], *be2 = (const float*)d_in[11];
    const float* g3 = (const float*)d_in[12], *be3 = (const float*)d_in[13];
    const float* Wq1 = (const float*)d_in[14], *bq1 = (const float*)d_in[15];
    const float* Wk1 = (const float*)d_in[16], *bk1 = (const float*)d_in[17];
    const float* Wv1 = (const float*)d_in[18], *bv1 = (const float*)d_in[19];
    const float* Wo1 = (const float*)d_in[20], *bo1 = (const float*)d_in[21];
    const float* Wq2 = (const float*)d_in[22], *bq2 = (const float*)d_in[23];
    const float* Wk2 = (const float*)d_in[24], *bk2 = (const float*)d_in[25];
    const float* Wv2 = (const float*)d_in[26], *bv2 = (const float*)d_in[27];
    const float* Wo2 = (const float*)d_in[28], *bo2 = (const float*)d_in[29];
    const float* fW1 = (const float*)d_in[30], *fb1 = (const float*)d_in[31];
    const float* fW2 = (const float*)d_in[32], *fb2 = (const float*)d_in[33];

    char* ws = (char*)d_ws;
    const size_t U = (size_t)NROW * DD * 2;        // 16.78 MB
    float* x1 = (float*)(ws);                      // 2U f32  [ph4: en bf16 in 1st U; then x3 f32]
    u16* qb   = (u16*)(ws + 2 * U);                // 1U
    u16* vb   = (u16*)(ws + 3 * U);                // 1U
    u16* hb   = (u16*)(ws + 4 * U);                // 1U  [ph5: ff1]
    u16* kp   = (u16*)(ws + 5 * U);                // 1.75U (B,H,1792,64)
    u16* vpt  = (u16*)(ws + 5 * U + 7 * U / 4);    // 1.75U (B,H,64,1792)
    u16* wt   = (u16*)(ws + 8 * U + U / 2);        // 10 x 512KB bf16 transposed weights
    float* x2 = (float*)d_out;                     // d_out doubles as x2 (fully overwritten at end)
    u16* en = (u16*)(ws);                          // phase-4 alias of dead x1 slot
    float* x3 = x1;                                // phase-4 output slot
    float* x4 = (float*)(ws + 5 * U);              // phase-5 alias over kp/vpt (dead)
    u16* ff1 = hb;                                 // phase-5 alias

    W10 wp;
    const float* wsrc[10] = {Wq1, Wk1, Wv1, Wo1, Wq2, Wk2, Wv2, Wo2, fW1, fW2};
    for (int i = 0; i < 10; i++) wp.p[i] = wsrc[i];
    transpose_all_k<<<dim3(8, 8, 10), 256, 0, stream>>>(wp, wt);
    u16* tWq1 = wt,            *tWk1 = wt + 262144,   *tWv1 = wt + 2*262144, *tWo1 = wt + 3*262144;
    u16* tWq2 = wt + 4*262144, *tWk2 = wt + 5*262144, *tWv2 = wt + 6*262144, *tWo2 = wt + 7*262144;
    u16* tF1  = wt + 8*262144, *tF2  = wt + 9*262144;

    dim3 ggrid(4, 128);
    dim3 vtgrid(16, 8, 16);
    const float QSC = 0.18033688f;   // 0.125 * log2(e): folded into Q projection

    // phase 2: x1 = LN1(embed sum)   (f32)
    embed_ln_k<<<4096, 256, 0, stream>>>(in_ex, in_cat, in_res, in_pos,
                                         E_res, E_ex, E_cat, g1, be1, x1);

    // phase 3: self-attention; x2 = x1 + attn(x1) @ Wo1
    {
        FArgs fa;
        fa.W[0] = tWq1; fa.bias[0] = bq1; fa.C[0] = qb; fa.osc[0] = QSC;  fa.mode[0] = 0;
        fa.W[1] = tWk1; fa.bias[1] = bk1; fa.C[1] = kp; fa.osc[1] = 1.0f; fa.mode[1] = 1;
        fa.W[2] = tWv1; fa.bias[2] = bv1; fa.C[2] = vb; fa.osc[2] = 1.0f; fa.mode[2] = 0;
        fused_gemm_k<true><<<dim3(12, 128), 256, 0, stream>>>(x1, fa, NROW, 512);
    }
    pool_vt_k<<<vtgrid, 256, 0, stream>>>(vb, vpt);
    attn_k<<<1024, 512, 0, stream>>>(qb, kp, vpt, hb);
    gemm_k<false,false,true,false,false><<<ggrid, 256, 0, stream>>>(hb, tWo1, bo1, x1, x2, NROW, 512, 1.0f);

    // phase 4: cross-attention; x3 = x2 + attn(q=x2, kv=en) @ Wo2
    ln_k<true><<<4096, 256, 0, stream>>>(en_out, g2, be2, en);
    gemm_k<true,false,false,true,false><<<ggrid, 256, 0, stream>>>(x2, tWq2, bq2, nullptr, qb, NROW, 512, QSC);
    {
        FArgs fa;
        fa.W[0] = tWk2; fa.bias[0] = bk2; fa.C[0] = kp; fa.osc[0] = 1.0f; fa.mode[0] = 1;
        fa.W[1] = tWv2; fa.bias[1] = bv2; fa.C[1] = vb; fa.osc[1] = 1.0f; fa.mode[1] = 0;
        fa.W[2] = nullptr; fa.bias[2] = nullptr; fa.C[2] = nullptr; fa.osc[2] = 1.0f; fa.mode[2] = 0;
        fused_gemm_k<false><<<dim3(8, 128), 256, 0, stream>>>(en, fa, NROW, 512);
    }
    pool_vt_k<<<vtgrid, 256, 0, stream>>>(vb, vpt);
    attn_k<<<1024, 512, 0, stream>>>(qb, kp, vpt, hb);
    gemm_k<false,false,true,false,false><<<ggrid, 256, 0, stream>>>(hb, tWo2, bo2, x2, x3, NROW, 512, 1.0f);

    // phase 5: x4 = LN3(x3); out = x4 + relu(x4@fW1+fb1)@fW2+fb2
    ln_k<false><<<4096, 256, 0, stream>>>(x3, g3, be3, x4);
    gemm_k<true,true,false,true,false><<<ggrid, 256, 0, stream>>>(x4, tF1, fb1, nullptr, ff1, NROW, 512, 1.0f);
    gemm_k<false,false,true,false,false><<<ggrid, 256, 0, stream>>>(ff1, tF2, fb2, x4, (float*)d_out, NROW, 512, 1.0f);
}